// Round 17
// baseline (583.186 us; speedup 1.0000x reference)
//
#include <hip/hip_runtime.h>
#include <hip/hip_bf16.h>
#include <stdint.h>
#include <math.h>

#define S_LEN 2048
#define DMODEL 1024
#define NHEAD 16
#define DHEAD 64
#define FFDIM 4096
#define NLAYER 2

using bf16 = __hip_bfloat16;
typedef __attribute__((ext_vector_type(8))) short bf16x8;
typedef __attribute__((ext_vector_type(4))) float f32x4;
typedef __attribute__((ext_vector_type(16))) float f32x16;
typedef __attribute__((ext_vector_type(4))) int i32x4;

#define MFMA16x16(A, B, C) __builtin_amdgcn_mfma_f32_16x16x32_bf16(A, B, C, 0, 0, 0)
#define MFMA32x32(A, B, C) __builtin_amdgcn_mfma_f32_32x32x16_bf16(A, B, C, 0, 0, 0)
#define EXP2(x) __builtin_amdgcn_exp2f(x)

__device__ __forceinline__ float bf2f(uint32_t u16bits) {
  union { uint32_t i; float f; } x;
  x.i = u16bits << 16;
  return x.f;
}
__device__ __forceinline__ uint16_t f2bf(float f) {
  return __builtin_bit_cast(uint16_t, __float2bfloat16(f));
}

// v_cvt_pk_bf16_f32: pack two f32 -> one dword of 2 bf16 (no builtin on gfx950)
__device__ __forceinline__ uint32_t cvtpk(float lo, float hi) {
  uint32_t r;
  asm("v_cvt_pk_bf16_f32 %0, %1, %2" : "=v"(r) : "v"(lo), "v"(hi));
  return r;
}
// v_permlane32_swap_b32
__device__ __forceinline__ void pl32swap(uint32_t& a, uint32_t& b) {
#if __has_builtin(__builtin_amdgcn_permlane32_swap)
  typedef __attribute__((ext_vector_type(2))) int i32x2;
  i32x2 r = __builtin_amdgcn_permlane32_swap((int)a, (int)b, false, false);
  a = (uint32_t)r.x;
  b = (uint32_t)r.y;
#else
  asm volatile("v_permlane32_swap_b32 %0, %1" : "+v"(a), "+v"(b));
#endif
}

// ---------------------------------------------------------------------------
// Weight cast + transpose: in fp32 (R x C)  ->  out bf16 (C x R)
// ---------------------------------------------------------------------------
__global__ __launch_bounds__(256) void k_tcast(const float* __restrict__ in,
                                               bf16* __restrict__ out,
                                               int R, int C) {
  __shared__ float tl[32][33];
  int t = threadIdx.x;
  int r0 = blockIdx.y * 32, c0 = blockIdx.x * 32;
  int cl = t & 31, rl = t >> 5;
#pragma unroll
  for (int i = 0; i < 4; ++i)
    tl[rl + i * 8][cl] = in[(size_t)(r0 + rl + i * 8) * C + c0 + cl];
  __syncthreads();
#pragma unroll
  for (int i = 0; i < 4; ++i)
    out[(size_t)(c0 + rl + i * 8) * R + r0 + cl] = __float2bfloat16(tl[cl][rl + i * 8]);
}

// ---------------------------------------------------------------------------
// LayerNorm helpers
// ---------------------------------------------------------------------------
__device__ __forceinline__ void ln_store4(bf16* p, float a, float b, float c, float d) {
  uint2 u;
  u.x = (uint32_t)f2bf(a) | ((uint32_t)f2bf(b) << 16);
  u.y = (uint32_t)f2bf(c) | ((uint32_t)f2bf(d) << 16);
  *(uint2*)p = u;
}
__device__ __forceinline__ void ln_store4(float* p, float a, float b, float c, float d) {
  *(float4*)p = make_float4(a, b, c, d);
}

// row-wide (1024) LN from 4 per-thread values; block = 256 threads
template <typename OUT>
__device__ __forceinline__ void ln_rowcore(float v0, float v1, float v2, float v3,
                                           const float* __restrict__ g,
                                           const float* __restrict__ b,
                                           OUT* __restrict__ yrow, int t) {
  float s = v0 + v1 + v2 + v3;
  float s2 = v0 * v0 + v1 * v1 + v2 * v2 + v3 * v3;
#pragma unroll
  for (int off = 32; off > 0; off >>= 1) {
    s += __shfl_down(s, off);
    s2 += __shfl_down(s2, off);
  }
  __shared__ float red[8];
  int w = t >> 6;
  if ((t & 63) == 0) { red[w] = s; red[4 + w] = s2; }
  __syncthreads();
  s = red[0] + red[1] + red[2] + red[3];
  s2 = red[4] + red[5] + red[6] + red[7];
  float mean = s * (1.0f / DMODEL);
  float var = s2 * (1.0f / DMODEL) - mean * mean;
  float rstd = rsqrtf(var + 1e-5f);
  float4 gv = ((const float4*)g)[t];
  float4 bv = ((const float4*)b)[t];
  ln_store4(yrow + t * 4, (v0 - mean) * rstd * gv.x + bv.x,
            (v1 - mean) * rstd * gv.y + bv.y, (v2 - mean) * rstd * gv.z + bv.z,
            (v3 - mean) * rstd * gv.w + bv.w);
}

template <typename OUT>
__global__ __launch_bounds__(256) void k_ln(const float* __restrict__ h,
                                            const float* __restrict__ g,
                                            const float* __restrict__ b,
                                            OUT* __restrict__ y) {
  int row = blockIdx.x, t = threadIdx.x;
  const float4 v = ((const float4*)(h + (size_t)row * DMODEL))[t];
  ln_rowcore<OUT>(v.x, v.y, v.z, v.w, g, b, y + (size_t)row * DMODEL, t);
}

// ---------------------------------------------------------------------------
// Fused split-K merge + residual + LayerNorm:
//   hnew = hb + bias + sum_ks part[ks];  hb := hnew;  y := LN(hnew; g,b)
// ---------------------------------------------------------------------------
template <int KS, typename OUT>
__global__ __launch_bounds__(256) void k_redln(const float* __restrict__ part,
                                               const float* __restrict__ bias,
                                               float* __restrict__ hb,
                                               const float* __restrict__ g,
                                               const float* __restrict__ b,
                                               OUT* __restrict__ y) {
  int row = blockIdx.x, t = threadIdx.x;
  size_t base = (size_t)row * DMODEL + t * 4;
  float4 r = *(const float4*)(hb + base);
  float4 bv = *(const float4*)(bias + t * 4);
  float v0 = r.x + bv.x, v1 = r.y + bv.y, v2 = r.z + bv.z, v3 = r.w + bv.w;
#pragma unroll
  for (int ks = 0; ks < KS; ++ks) {
    float4 p = *(const float4*)(part + (size_t)ks * (S_LEN * DMODEL) + base);
    v0 += p.x; v1 += p.y; v2 += p.z; v3 += p.w;
  }
  *(float4*)(hb + base) = make_float4(v0, v1, v2, v3);
  ln_rowcore<OUT>(v0, v1, v2, v3, g, b, y + (size_t)row * DMODEL, t);
}

// ---------------------------------------------------------------------------
// Fused RoPE (q,k) + V transpose. Grid (S/64, NHEAD), 256 threads.
// ---------------------------------------------------------------------------
__global__ __launch_bounds__(256) void k_ropetv(const bf16* __restrict__ qkv,
                                                const float* __restrict__ fcos,
                                                const float* __restrict__ fsin,
                                                bf16* __restrict__ qr,
                                                bf16* __restrict__ kr,
                                                bf16* __restrict__ vT) {
  __shared__ bf16 tl[64][65];
  int t = threadIdx.x;
  int hh = blockIdx.y;
  int sb = blockIdx.x * 64;
#pragma unroll
  for (int i = 0; i < 8; ++i) {
    int e = i * 256 + t;
    int p = e & 31, sl = e >> 5;
    int s = sb + sl;
    float c = fcos[s * 32 + p], sn = fsin[s * 32 + p];
    int colq = hh * DHEAD + 2 * p;
    uint32_t rq = *(const uint32_t*)(qkv + (size_t)s * 3 * DMODEL + colq);
    uint32_t rk = *(const uint32_t*)(qkv + (size_t)s * 3 * DMODEL + DMODEL + colq);
    {
      float te = bf2f(rq & 0xffffu), to = bf2f(rq >> 16);
      uint32_t outv = (uint32_t)f2bf(te * c - to * sn) | ((uint32_t)f2bf(te * sn + to * c) << 16);
      *(uint32_t*)(qr + (size_t)s * DMODEL + colq) = outv;
    }
    {
      float te = bf2f(rk & 0xffffu), to = bf2f(rk >> 16);
      uint32_t outv = (uint32_t)f2bf(te * c - to * sn) | ((uint32_t)f2bf(te * sn + to * c) << 16);
      *(uint32_t*)(kr + (size_t)s * DMODEL + colq) = outv;
    }
  }
#pragma unroll
  for (int i = 0; i < 16; ++i) {
    int e = i * 256 + t;
    int sl = e >> 6, d = e & 63;
    tl[sl][d] = qkv[(size_t)(sb + sl) * 3 * DMODEL + 2 * DMODEL + hh * DHEAD + d];
  }
  __syncthreads();
#pragma unroll
  for (int i = 0; i < 16; ++i) {
    int e = i * 256 + t;
    int d = e >> 6, sl = e & 63;
    vT[(size_t)(hh * DHEAD + d) * S_LEN + sb + sl] = tl[sl][d];
  }
}

// ---------------------------------------------------------------------------
// GEMM v8: r16 counted-vmcnt pipeline + ASM ds_read (the missing piece).
// r16 diagnosis: HIP-level ds_reads from As/Bs force the compiler to insert
// its own s_waitcnt vmcnt(0) before them (can't prove in-flight
// global_load_lds target the other buffer) — the counted vmcnt(8) was dead.
// Fix: inline-asm ds_read_b128 on raw LDS byte addresses (invisible to the
// dependency tracker) + explicit lgkmcnt(0) + sched_barrier(0) before MFMA
// (rule #18). vmcnt never drains to 0 in the main loop.
// EPI 0: bias -> bf16.  EPI 2: gelu(bias) -> bf16.  EPI 3: raw fp32 partial.
// ---------------------------------------------------------------------------
template <int EPI, int BM>
__global__ __launch_bounds__(256) void k_gemm2(const bf16* __restrict__ A,
                                               const bf16* __restrict__ BT,
                                               const float* __restrict__ bias,
                                               void* __restrict__ out,
                                               int M, int N, int K, int Kc) {
  constexpr int MF = BM / 32;  // m-frags per wave
  __shared__ bf16 As[2][BM * 64];
  __shared__ bf16 Bs[2][128 * 64];
  int t = threadIdx.x;
  int w = t >> 6, l = t & 63, lr = l & 15, lg = l >> 4;

  int nxy = gridDim.x * gridDim.y;
  int bid = blockIdx.y * gridDim.x + blockIdx.x;
  int chk8 = nxy >> 3;
  int swz = (bid & 7) * chk8 + (bid >> 3);
  int bx = swz % gridDim.x, by = swz / gridDim.x;
  int bm = bx * BM, bn = by * 128;
  int k0 = blockIdx.z * Kc;
  int wm = (w >> 1) * (BM / 2), wn = (w & 1) * 64;

  f32x4 zero4 = {0.f, 0.f, 0.f, 0.f};
  f32x4 acc[MF][4];
#pragma unroll
  for (int mf = 0; mf < MF; ++mf)
#pragma unroll
    for (int nf = 0; nf < 4; ++nf) acc[mf][nf] = zero4;

  auto stage = [&](int buf, int kk) {
#pragma unroll
    for (int i = 0; i < BM / 32; ++i) {
      int chunk = i * 256 + t;
      int row = chunk >> 3;
      int scol = ((chunk ^ row) & 7) << 3;
      __builtin_amdgcn_global_load_lds(
          (__attribute__((address_space(1))) void*)(A + (size_t)(bm + row) * K + kk + scol),
          (__attribute__((address_space(3))) void*)(&As[buf][chunk * 8]), 16, 0, 0);
    }
#pragma unroll
    for (int i = 0; i < 4; ++i) {
      int chunk = i * 256 + t;
      int row = chunk >> 3;
      int scol = ((chunk ^ row) & 7) << 3;
      __builtin_amdgcn_global_load_lds(
          (__attribute__((address_space(1))) void*)(BT + (size_t)(bn + row) * K + kk + scol),
          (__attribute__((address_space(3))) void*)(&Bs[buf][chunk * 8]), 16, 0, 0);
    }
  };

  // per-lane LDS byte addresses of the 8 fragment slots (h=0..1 folded below)
  uint32_t aoff[MF], boff[4];
#pragma unroll
  for (int mf = 0; mf < MF; ++mf) {
    int row = wm + mf * 16 + lr;
    aoff[mf] = (uint32_t)(row * 64 + ((lg ^ (row & 7)) << 3)) * 2;
  }
#pragma unroll
  for (int nf = 0; nf < 4; ++nf) {
    int row = wn + nf * 16 + lr;
    boff[nf] = (uint32_t)(row * 64 + ((lg ^ (row & 7)) << 3)) * 2;
  }
  // h=1 flips bit2 of the slot index: addr ^= (4<<3)*2 = 64 bytes
  uint32_t abase0 = (uint32_t)(uintptr_t)&As[0][0];
  uint32_t bbase0 = (uint32_t)(uintptr_t)&Bs[0][0];
  constexpr uint32_t ABUF = (uint32_t)(BM * 64 * 2);
  constexpr uint32_t BBUF = (uint32_t)(128 * 64 * 2);

  int nt = Kc / 64;
  stage(0, k0);
  stage(1, k0 + 64);  // 2 tiles in flight
  int cur = 0;
  for (int kt = 0; kt < nt; ++kt) {
    // wait for the OLDEST stage (tile kt) only; tile kt+1 stays in flight
    if (kt + 1 < nt) {
      if constexpr (BM == 128)
        asm volatile("s_waitcnt vmcnt(8)" ::: "memory");
      else
        asm volatile("s_waitcnt vmcnt(6)" ::: "memory");
    } else {
      asm volatile("s_waitcnt vmcnt(0)" ::: "memory");
    }
    __builtin_amdgcn_s_barrier();  // all waves' tile-kt loads landed
    __builtin_amdgcn_sched_barrier(0);
    // asm ds_read: invisible to compiler dep-tracking -> no auto vmcnt(0)
    bf16x8 af[2][MF], bfr[2][4];
    {
      uint32_t ab = abase0 + (cur ? ABUF : 0u);
      uint32_t bb = bbase0 + (cur ? BBUF : 0u);
#pragma unroll
      for (int h = 0; h < 2; ++h) {
#pragma unroll
        for (int mf = 0; mf < MF; ++mf) {
          uint32_t ad = ab + (aoff[mf] ^ (h ? 64u : 0u));
          asm volatile("ds_read_b128 %0, %1" : "=v"(af[h][mf]) : "v"(ad));
        }
#pragma unroll
        for (int nf = 0; nf < 4; ++nf) {
          uint32_t bd = bb + (boff[nf] ^ (h ? 64u : 0u));
          asm volatile("ds_read_b128 %0, %1" : "=v"(bfr[h][nf]) : "v"(bd));
        }
      }
    }
    asm volatile("s_waitcnt lgkmcnt(0)" ::: "memory");
    __builtin_amdgcn_sched_barrier(0);  // rule #18: pin MFMA after lgkm wait
    __builtin_amdgcn_s_barrier();       // all waves done reading buf[cur]
    if (kt + 2 < nt) stage(cur, k0 + (kt + 2) * 64);  // refill freed buffer
    __builtin_amdgcn_sched_barrier(0);
#pragma unroll
    for (int h = 0; h < 2; ++h)
#pragma unroll
      for (int mf = 0; mf < MF; ++mf)
#pragma unroll
        for (int nf = 0; nf < 4; ++nf)
          acc[mf][nf] = MFMA16x16(af[h][mf], bfr[h][nf], acc[mf][nf]);
    cur ^= 1;
  }

  if (EPI == 3) {
    float* outf = (float*)out + (size_t)blockIdx.z * ((size_t)M * N);
#pragma unroll
    for (int mf = 0; mf < MF; ++mf)
#pragma unroll
      for (int nf = 0; nf < 4; ++nf) {
        int col = bn + wn + nf * 16 + lr;
        int row0 = bm + wm + mf * 16 + lg * 4;
#pragma unroll
        for (int r = 0; r < 4; ++r)
          outf[(size_t)(row0 + r) * N + col] = acc[mf][nf][r];
      }
  } else {
    bf16* outb = (bf16*)out;
#pragma unroll
    for (int mf = 0; mf < MF; ++mf)
#pragma unroll
      for (int nf = 0; nf < 4; ++nf) {
        int col = bn + wn + nf * 16 + lr;
        float bv = bias[col];
        int row0 = bm + wm + mf * 16 + lg * 4;
#pragma unroll
        for (int r = 0; r < 4; ++r) {
          float v = acc[mf][nf][r] + bv;
          if (EPI == 2)
            v = 0.5f * v * (1.0f + tanhf(0.7978845608028654f * (v + 0.044715f * v * v * v)));
          outb[(size_t)(row0 + r) * N + col] = __float2bfloat16(v);
        }
      }
  }
}

// ---------------------------------------------------------------------------
// Flash attention v8: r16 body + wave-uniform segment-bias fast path
// (32-aligned tiles vs 512-aligned segment bounds -> ~98% of tiles are
// entirely in/out; replaces 16 iadd+16 cmp+16 cndmask+16 fma with 16 fma).
// ---------------------------------------------------------------------------
#define ATTN_TILE(KC0, KC1, KC2, KC3, KN0, KN1, KN2, KN3, IT)                  \
  {                                                                            \
    const int j0 = jbase + (IT) * 32;                                          \
    f32x16 sC;                                                                 \
    _Pragma("unroll") for (int r = 0; r < 16; ++r) sC[r] = 0.f;                \
    __builtin_amdgcn_s_setprio(1);                                             \
    sC = MFMA32x32(KC0, qf0, sC);                                              \
    sC = MFMA32x32(KC1, qf1, sC);                                              \
    sC = MFMA32x32(KC2, qf2, sC);                                              \
    sC = MFMA32x32(KC3, qf3, sC);                                              \
    __builtin_amdgcn_s_setprio(0);                                             \
    const bf16* vbase = vrow + j0;                                             \
    bf16x8 va00 = *(const bf16x8*)(vbase);                                     \
    bf16x8 va01 = *(const bf16x8*)(vbase + 16);                                \
    bf16x8 va10 = *(const bf16x8*)(vbase + 32 * S_LEN);                        \
    bf16x8 va11 = *(const bf16x8*)(vbase + 32 * S_LEN + 16);                   \
    {                                                                          \
      int jn = j0 + 32;                                                        \
      int jmax = jbase + 480;                                                  \
      jn = (jn > jmax) ? jmax : jn;                                            \
      const bf16* kn = krow + (size_t)jn * DMODEL;                             \
      KN0 = *(const bf16x8*)(kn);                                              \
      KN1 = *(const bf16x8*)(kn + 16);                                         \
      KN2 = *(const bf16x8*)(kn + 32);                                         \
      KN3 = *(const bf16x8*)(kn + 48);                                         \
    }                                                                          \
    int allin = (j0 >= sl0) & (j0 + 32 <= sh0);                                \
    int allout = (j0 + 32 <= sl0) | (j0 >= sh0);                               \
    if (__builtin_expect(__all(allin | allout), 1)) {                          \
      float fb = allin ? LOG2E : 0.0f;                                         \
      _Pragma("unroll") for (int r = 0; r < 16; ++r) sC[r] = sC[r] * C1 + fb;  \
    } else {                                                                   \
      int tt = j0 + hi * 4 - sl0;                                              \
      _Pragma("unroll") for (int r = 0; r < 16; ++r) {                         \
        int ku = tt + ((r & 3) + 8 * (r >> 2));                                \
        float fb = ((uint32_t)ku < spanu) ? LOG2E : 0.0f;                      \
        sC[r] = sC[r] * C1 + fb;                                               \
      }                                                                        \
    }                                                                          \
    float rm = sC[0];                                                          \
    _Pragma("unroll") for (int r = 1; r < 16; ++r) rm = fmaxf(rm, sC[r]);      \
    uint32_t ra = __builtin_bit_cast(uint32_t, rm), rb = ra;                   \
    pl32swap(ra, rb);                                                          \
    float rmax =                                                               \
        fmaxf(__builtin_bit_cast(float, ra), __builtin_bit_cast(float, rb));   \
    if (__any(rmax > m_r + 8.0f)) {                                            \
      float mn = fmaxf(m_r, rmax);                                             \
      float fs = EXP2(m_r - mn);                                               \
      m_r = mn;                                                                \
      l_r *= fs;                                                               \
      _Pragma("unroll") for (int r = 0; r < 16; ++r) {                         \
        oC0[r] *= fs;                                                          \
        oC1[r] *= fs;                                                          \
      }                                                                        \
    }                                                                          \
    _Pragma("unroll") for (int r = 0; r < 16; ++r) {                           \
      float pv = EXP2(sC[r] - m_r);                                            \
      sC[r] = pv;                                                              \
      l_r += pv;                                                               \
    }                                                                          \
    uint32_t u0 = cvtpk(sC[0], sC[1]), u1 = cvtpk(sC[2], sC[3]);               \
    uint32_t u2 = cvtpk(sC[4], sC[5]), u3 = cvtpk(sC[6], sC[7]);               \
    uint32_t u4 = cvtpk(sC[8], sC[9]), u5 = cvtpk(sC[10], sC[11]);             \
    uint32_t u6 = cvtpk(sC[12], sC[13]), u7 = cvtpk(sC[14], sC[15]);           \
    pl32swap(u0, u2);                                                          \
    pl32swap(u1, u3);                                                          \
    pl32swap(u4, u6);                                                          \
    pl32swap(u5, u7);                                                          \
    i32x4 pi0 = {(int)u0, (int)u1, (int)u2, (int)u3};                          \
    i32x4 pi1 = {(int)u4, (int)u5, (int)u6, (int)u7};                          \
    bf16x8 pb0 = __builtin_bit_cast(bf16x8, pi0);                              \
    bf16x8 pb1 = __builtin_bit_cast(bf16x8, pi1);                              \
    __builtin_amdgcn_s_setprio(1);                                             \
    oC0 = MFMA32x32(va00, pb0, oC0);                                           \
    oC0 = MFMA32x32(va01, pb1, oC0);                                           \
    oC1 = MFMA32x32(va10, pb0, oC1);                                           \
    oC1 = MFMA32x32(va11, pb1, oC1);                                           \
    __builtin_amdgcn_s_setprio(0);                                             \
  }

__global__ __launch_bounds__(256, 4) void k_attn(const bf16* __restrict__ qr,
                                                 const bf16* __restrict__ kr,
                                                 const bf16* __restrict__ vT,
                                                 const int* __restrict__ offs,
                                                 bf16* __restrict__ ao) {
  __shared__ float oO[4][64][33];
  __shared__ float mM[4][32];
  __shared__ float lL[4][32];

  int t = threadIdx.x, w = t >> 6, l = t & 63;
  int ql = l & 31, hi = l >> 5, hi8 = hi * 8;
  int hh = blockIdx.x, qb = blockIdx.y * 32;
  int h64 = hh * DHEAD;

  constexpr float LOG2E = 1.4426950408889634f;
  constexpr float C1 = 0.125f * LOG2E;

  int q = qb + ql;
  int o0 = offs[0], o1 = offs[1], o2 = offs[2], o3 = offs[3], o4 = offs[4];
  int sl0 = -1073741824, sh0 = 1073741824;
  sl0 = (o0 <= q) ? o0 : sl0;
  sl0 = (o1 <= q) ? o1 : sl0;
  sl0 = (o2 <= q) ? o2 : sl0;
  sl0 = (o3 <= q) ? o3 : sl0;
  sl0 = (o4 <= q) ? o4 : sl0;
  sh0 = (o4 > q) ? o4 : sh0;
  sh0 = (o3 > q) ? o3 : sh0;
  sh0 = (o2 > q) ? o2 : sh0;
  sh0 = (o1 > q) ? o1 : sh0;
  sh0 = (o0 > q) ? o0 : sh0;
  uint32_t spanu = (uint32_t)(sh0 - sl0);

  const bf16* qbase = qr + (size_t)q * DMODEL + h64 + hi8;
  bf16x8 qf0 = *(const bf16x8*)(qbase);
  bf16x8 qf1 = *(const bf16x8*)(qbase + 16);
  bf16x8 qf2 = *(const bf16x8*)(qbase + 32);
  bf16x8 qf3 = *(const bf16x8*)(qbase + 48);

  f32x16 oC0, oC1;
#pragma unroll
  for (int r = 0; r < 16; ++r) { oC0[r] = 0.f; oC1[r] = 0.f; }
  float m_r = -1e30f, l_r = 0.f;

  const bf16* vrow = vT + (size_t)(h64 + ql) * S_LEN + hi8;
  const bf16* krow = kr + (size_t)ql * DMODEL + h64 + hi8;
  int jbase = w * 512;

  bf16x8 kA0, kA1, kA2, kA3, kB0, kB1, kB2, kB3;
  {
    const bf16* kb = krow + (size_t)jbase * DMODEL;
    kA0 = *(const bf16x8*)(kb);
    kA1 = *(const bf16x8*)(kb + 16);
    kA2 = *(const bf16x8*)(kb + 32);
    kA3 = *(const bf16x8*)(kb + 48);
  }

  for (int itp = 0; itp < 8; ++itp) {
    ATTN_TILE(kA0, kA1, kA2, kA3, kB0, kB1, kB2, kB3, itp * 2);
    ATTN_TILE(kB0, kB1, kB2, kB3, kA0, kA1, kA2, kA3, itp * 2 + 1);
  }

  {
    uint32_t la = __builtin_bit_cast(uint32_t, l_r), lb = la;
    pl32swap(la, lb);
    l_r = __builtin_bit_cast(float, la) + __builtin_bit_cast(float, lb);
  }
  if (hi == 0) {
    mM[w][ql] = m_r;
    lL[w][ql] = l_r;
  }
#pragma unroll
  for (int r = 0; r < 16; ++r) {
    int d = (r & 3) + 8 * (r >> 2) + 4 * hi;
    oO[w][d][ql] = oC0[r];
    oO[w][d + 32][ql] = oC1[r];
  }
  __syncthreads();

  {
    int mq = t & 31, dbse = (t >> 5) * 8;
    float m0 = mM[0][mq], m1 = mM[1][mq], m2 = mM[2][mq], m3 = mM[3][mq];
    float ms = fmaxf(fmaxf(m0, m1), fmaxf(m2, m3));
    float a0 = EXP2(m0 - ms), a1 = EXP2(m1 - ms), a2 = EXP2(m2 - ms), a3 = EXP2(m3 - ms);
    float ll = a0 * lL[0][mq] + a1 * lL[1][mq] + a2 * lL[2][mq] + a3 * lL[3][mq];
    float inv = 1.0f / ll;
    uint4 pkv;
    uint32_t pw[4];
#pragma unroll
    for (int i = 0; i < 4; ++i) {
      int d0 = dbse + 2 * i, d1 = dbse + 2 * i + 1;
      float e0 = (a0 * oO[0][d0][mq] + a1 * oO[1][d0][mq] + a2 * oO[2][d0][mq] +
                  a3 * oO[3][d0][mq]) * inv;
      float e1 = (a0 * oO[0][d1][mq] + a1 * oO[1][d1][mq] + a2 * oO[2][d1][mq] +
                  a3 * oO[3][d1][mq]) * inv;
      pw[i] = (uint32_t)f2bf(e0) | ((uint32_t)f2bf(e1) << 16);
    }
    pkv.x = pw[0]; pkv.y = pw[1]; pkv.z = pw[2]; pkv.w = pw[3];
    *(uint4*)(ao + (size_t)(qb + mq) * DMODEL + h64 + dbse) = pkv;
  }
}

// ---------------------------------------------------------------------------
extern "C" void kernel_launch(void* const* d_in, const int* in_sizes, int n_in,
                              void* d_out, int out_size, void* d_ws, size_t ws_size,
                              hipStream_t stream) {
  const float* x = (const float*)d_in[0];
  const int* offs = (const int*)d_in[1];
  const float* fcos = (const float*)d_in[2];
  const float* fsin = (const float*)d_in[3];
  const float* ln0g = (const float*)d_in[4];
  const float* ln0b = (const float*)d_in[5];
  const float* ln1g = (const float*)d_in[6];
  const float* ln1b = (const float*)d_in[7];
  const float* wqkv = (const float*)d_in[8];
  const float* bqkv = (const float*)d_in[9];
  const float* wo = (const float*)d_in[10];
  const float* bo = (const float*)d_in[11];
  const float* wu = (const float*)d_in[12];
  const float* bu = (const float*)d_in[13];
  const float* wd = (const float*)d_in[14];
  const float* bd = (const float*)d_in[15];
  const float* lnfg = (const float*)d_in[16];
  const float* lnfb = (const float*)d_in[17];

  char* ws = (char*)d_ws;
  size_t off = 0;
  auto alloc = [&](size_t bytes) -> void* {
    void* p = ws + off;
    off += (bytes + 255) & ~(size_t)255;
    return p;
  };
  bf16* wqkvT = (bf16*)alloc((size_t)NLAYER * 3 * DMODEL * DMODEL * 2);
  bf16* woT = (bf16*)alloc((size_t)NLAYER * DMODEL * DMODEL * 2);
  bf16* wuT = (bf16*)alloc((size_t)NLAYER * DMODEL * FFDIM * 2);
  bf16* wdT = (bf16*)alloc((size_t)NLAYER * FFDIM * DMODEL * 2);
  float* hbuf = (float*)alloc((size_t)S_LEN * DMODEL * 4);
  bf16* ybuf = (bf16*)alloc((size_t)S_LEN * DMODEL * 2);   // partDN head space
  bf16* qkv = (bf16*)alloc((size_t)S_LEN * 3 * DMODEL * 2);
  bf16* qrb = (bf16*)alloc((size_t)S_LEN * DMODEL * 2);
  bf16* krb = (bf16*)alloc((size_t)S_LEN * DMODEL * 2);
  bf16* vTb = (bf16*)alloc((size_t)S_LEN * DMODEL * 2);
  bf16* aob = (bf16*)alloc((size_t)S_LEN * DMODEL * 2);
  bf16* midb = (bf16*)alloc((size_t)S_LEN * FFDIM * 2);
  bf16* ybuf2 = (bf16*)alloc((size_t)S_LEN * DMODEL * 2);  // LN outputs (A operand)

  float* partWO = (float*)qkv;
  float* partDN = (float*)ybuf;

  for (int ly = 0; ly < NLAYER; ++ly) {
    k_tcast<<<dim3(3 * DMODEL / 32, DMODEL / 32), 256, 0, stream>>>(
        wqkv + (size_t)ly * DMODEL * 3 * DMODEL, wqkvT + (size_t)ly * 3 * DMODEL * DMODEL, DMODEL, 3 * DMODEL);
    k_tcast<<<dim3(DMODEL / 32, DMODEL / 32), 256, 0, stream>>>(
        wo + (size_t)ly * DMODEL * DMODEL, woT + (size_t)ly * DMODEL * DMODEL, DMODEL, DMODEL);
    k_tcast<<<dim3(FFDIM / 32, DMODEL / 32), 256, 0, stream>>>(
        wu + (size_t)ly * DMODEL * FFDIM, wuT + (size_t)ly * DMODEL * FFDIM, DMODEL, FFDIM);
    k_tcast<<<dim3(DMODEL / 32, FFDIM / 32), 256, 0, stream>>>(
        wd + (size_t)ly * FFDIM * DMODEL, wdT + (size_t)ly * FFDIM * DMODEL, FFDIM, DMODEL);
  }
  hipMemcpyAsync(hbuf, x, (size_t)S_LEN * DMODEL * 4, hipMemcpyDeviceToDevice, stream);

  k_ln<bf16><<<S_LEN, 256, 0, stream>>>(hbuf, ln0g, ln0b, ybuf2);

  for (int ly = 0; ly < NLAYER; ++ly) {
    // QKV: M=2048, N=3072, K=1024  (grid 16x24 = 384)
    k_gemm2<0, 128><<<dim3(S_LEN / 128, 3 * DMODEL / 128, 1), 256, 0, stream>>>(
        ybuf2, wqkvT + (size_t)ly * 3 * DMODEL * DMODEL, bqkv + ly * 3 * DMODEL, qkv,
        S_LEN, 3 * DMODEL, DMODEL, DMODEL);
    k_ropetv<<<dim3(S_LEN / 64, NHEAD), 256, 0, stream>>>(qkv, fcos, fsin, qrb, krb, vTb);
    k_attn<<<dim3(NHEAD, S_LEN / 32), 256, 0, stream>>>(qrb, krb, vTb, offs, aob);
    // WO: M=2048, N=1024, K=1024, split-K 2, BM=64  (xy grid 32x8 = 256)
    k_gemm2<3, 64><<<dim3(S_LEN / 64, DMODEL / 128, 2), 256, 0, stream>>>(
        aob, woT + (size_t)ly * DMODEL * DMODEL, nullptr, partWO,
        S_LEN, DMODEL, DMODEL, DMODEL / 2);
    k_redln<2, bf16><<<S_LEN, 256, 0, stream>>>(
        partWO, bo + ly * DMODEL, hbuf, ln1g + ly * DMODEL, ln1b + ly * DMODEL, ybuf2);
    // UP: M=2048, N=4096, K=1024  (grid 16x32 = 512)
    k_gemm2<2, 128><<<dim3(S_LEN / 128, FFDIM / 128, 1), 256, 0, stream>>>(
        ybuf2, wuT + (size_t)ly * DMODEL * FFDIM, bu + ly * FFDIM, midb,
        S_LEN, FFDIM, DMODEL, DMODEL);
    // DOWN: M=2048, N=1024, K=4096, split-K 4, BM=128  (xy grid 16x8 = 128)
    k_gemm2<3, 128><<<dim3(S_LEN / 128, DMODEL / 128, 4), 256, 0, stream>>>(
        midb, wdT + (size_t)ly * FFDIM * DMODEL, nullptr, partDN,
        S_LEN, DMODEL, FFDIM, FFDIM / 4);
    if (ly + 1 < NLAYER) {
      k_redln<4, bf16><<<S_LEN, 256, 0, stream>>>(
          partDN, bd + ly * DMODEL, hbuf, ln0g + (ly + 1) * DMODEL,
          ln0b + (ly + 1) * DMODEL, ybuf2);
    } else {
      k_redln<4, float><<<S_LEN, 256, 0, stream>>>(
          partDN, bd + ly * DMODEL, hbuf, lnfg, lnfb, (float*)d_out);
    }
  }
}

// Round 18
// 401.345 us; speedup vs baseline: 1.4531x; 1.4531x over previous
//
#include <hip/hip_runtime.h>
#include <hip/hip_bf16.h>
#include <stdint.h>
#include <math.h>

#define S_LEN 2048
#define DMODEL 1024
#define NHEAD 16
#define DHEAD 64
#define FFDIM 4096
#define NLAYER 2

using bf16 = __hip_bfloat16;
typedef __attribute__((ext_vector_type(8))) short bf16x8;
typedef __attribute__((ext_vector_type(4))) float f32x4;
typedef __attribute__((ext_vector_type(16))) float f32x16;
typedef __attribute__((ext_vector_type(4))) int i32x4;

#define MFMA16x16(A, B, C) __builtin_amdgcn_mfma_f32_16x16x32_bf16(A, B, C, 0, 0, 0)
#define MFMA32x32(A, B, C) __builtin_amdgcn_mfma_f32_32x32x16_bf16(A, B, C, 0, 0, 0)
#define EXP2(x) __builtin_amdgcn_exp2f(x)

__device__ __forceinline__ float bf2f(uint32_t u16bits) {
  union { uint32_t i; float f; } x;
  x.i = u16bits << 16;
  return x.f;
}
__device__ __forceinline__ uint16_t f2bf(float f) {
  return __builtin_bit_cast(uint16_t, __float2bfloat16(f));
}

// v_cvt_pk_bf16_f32: pack two f32 -> one dword of 2 bf16 (no builtin on gfx950)
__device__ __forceinline__ uint32_t cvtpk(float lo, float hi) {
  uint32_t r;
  asm("v_cvt_pk_bf16_f32 %0, %1, %2" : "=v"(r) : "v"(lo), "v"(hi));
  return r;
}
// v_permlane32_swap_b32
__device__ __forceinline__ void pl32swap(uint32_t& a, uint32_t& b) {
#if __has_builtin(__builtin_amdgcn_permlane32_swap)
  typedef __attribute__((ext_vector_type(2))) int i32x2;
  i32x2 r = __builtin_amdgcn_permlane32_swap((int)a, (int)b, false, false);
  a = (uint32_t)r.x;
  b = (uint32_t)r.y;
#else
  asm volatile("v_permlane32_swap_b32 %0, %1" : "+v"(a), "+v"(b));
#endif
}

// ---------------------------------------------------------------------------
// Weight cast + transpose: in fp32 (R x C)  ->  out bf16 (C x R)
// ---------------------------------------------------------------------------
__global__ __launch_bounds__(256) void k_tcast(const float* __restrict__ in,
                                               bf16* __restrict__ out,
                                               int R, int C) {
  __shared__ float tl[32][33];
  int t = threadIdx.x;
  int r0 = blockIdx.y * 32, c0 = blockIdx.x * 32;
  int cl = t & 31, rl = t >> 5;
#pragma unroll
  for (int i = 0; i < 4; ++i)
    tl[rl + i * 8][cl] = in[(size_t)(r0 + rl + i * 8) * C + c0 + cl];
  __syncthreads();
#pragma unroll
  for (int i = 0; i < 4; ++i)
    out[(size_t)(c0 + rl + i * 8) * R + r0 + cl] = __float2bfloat16(tl[cl][rl + i * 8]);
}

// ---------------------------------------------------------------------------
// LayerNorm helpers
// ---------------------------------------------------------------------------
__device__ __forceinline__ void ln_store4(bf16* p, float a, float b, float c, float d) {
  uint2 u;
  u.x = (uint32_t)f2bf(a) | ((uint32_t)f2bf(b) << 16);
  u.y = (uint32_t)f2bf(c) | ((uint32_t)f2bf(d) << 16);
  *(uint2*)p = u;
}
__device__ __forceinline__ void ln_store4(float* p, float a, float b, float c, float d) {
  *(float4*)p = make_float4(a, b, c, d);
}

// row-wide (1024) LN from 4 per-thread values; block = 256 threads
template <typename OUT>
__device__ __forceinline__ void ln_rowcore(float v0, float v1, float v2, float v3,
                                           const float* __restrict__ g,
                                           const float* __restrict__ b,
                                           OUT* __restrict__ yrow, int t) {
  float s = v0 + v1 + v2 + v3;
  float s2 = v0 * v0 + v1 * v1 + v2 * v2 + v3 * v3;
#pragma unroll
  for (int off = 32; off > 0; off >>= 1) {
    s += __shfl_down(s, off);
    s2 += __shfl_down(s2, off);
  }
  __shared__ float red[8];
  int w = t >> 6;
  if ((t & 63) == 0) { red[w] = s; red[4 + w] = s2; }
  __syncthreads();
  s = red[0] + red[1] + red[2] + red[3];
  s2 = red[4] + red[5] + red[6] + red[7];
  float mean = s * (1.0f / DMODEL);
  float var = s2 * (1.0f / DMODEL) - mean * mean;
  float rstd = rsqrtf(var + 1e-5f);
  float4 gv = ((const float4*)g)[t];
  float4 bv = ((const float4*)b)[t];
  ln_store4(yrow + t * 4, (v0 - mean) * rstd * gv.x + bv.x,
            (v1 - mean) * rstd * gv.y + bv.y, (v2 - mean) * rstd * gv.z + bv.z,
            (v3 - mean) * rstd * gv.w + bv.w);
}

template <typename OUT>
__global__ __launch_bounds__(256) void k_ln(const float* __restrict__ h,
                                            const float* __restrict__ g,
                                            const float* __restrict__ b,
                                            OUT* __restrict__ y) {
  int row = blockIdx.x, t = threadIdx.x;
  const float4 v = ((const float4*)(h + (size_t)row * DMODEL))[t];
  ln_rowcore<OUT>(v.x, v.y, v.z, v.w, g, b, y + (size_t)row * DMODEL, t);
}

// ---------------------------------------------------------------------------
// Fused split-K merge + residual + LayerNorm:
//   hnew = hb + bias + sum_ks part[ks];  hb := hnew;  y := LN(hnew; g,b)
// ---------------------------------------------------------------------------
template <int KS, typename OUT>
__global__ __launch_bounds__(256) void k_redln(const float* __restrict__ part,
                                               const float* __restrict__ bias,
                                               float* __restrict__ hb,
                                               const float* __restrict__ g,
                                               const float* __restrict__ b,
                                               OUT* __restrict__ y) {
  int row = blockIdx.x, t = threadIdx.x;
  size_t base = (size_t)row * DMODEL + t * 4;
  float4 r = *(const float4*)(hb + base);
  float4 bv = *(const float4*)(bias + t * 4);
  float v0 = r.x + bv.x, v1 = r.y + bv.y, v2 = r.z + bv.z, v3 = r.w + bv.w;
#pragma unroll
  for (int ks = 0; ks < KS; ++ks) {
    float4 p = *(const float4*)(part + (size_t)ks * (S_LEN * DMODEL) + base);
    v0 += p.x; v1 += p.y; v2 += p.z; v3 += p.w;
  }
  *(float4*)(hb + base) = make_float4(v0, v1, v2, v3);
  ln_rowcore<OUT>(v0, v1, v2, v3, g, b, y + (size_t)row * DMODEL, t);
}

// ---------------------------------------------------------------------------
// Fused RoPE (q,k) + V transpose. Grid (S/64, NHEAD), 256 threads.
// ---------------------------------------------------------------------------
__global__ __launch_bounds__(256) void k_ropetv(const bf16* __restrict__ qkv,
                                                const float* __restrict__ fcos,
                                                const float* __restrict__ fsin,
                                                bf16* __restrict__ qr,
                                                bf16* __restrict__ kr,
                                                bf16* __restrict__ vT) {
  __shared__ bf16 tl[64][65];
  int t = threadIdx.x;
  int hh = blockIdx.y;
  int sb = blockIdx.x * 64;
#pragma unroll
  for (int i = 0; i < 8; ++i) {
    int e = i * 256 + t;
    int p = e & 31, sl = e >> 5;
    int s = sb + sl;
    float c = fcos[s * 32 + p], sn = fsin[s * 32 + p];
    int colq = hh * DHEAD + 2 * p;
    uint32_t rq = *(const uint32_t*)(qkv + (size_t)s * 3 * DMODEL + colq);
    uint32_t rk = *(const uint32_t*)(qkv + (size_t)s * 3 * DMODEL + DMODEL + colq);
    {
      float te = bf2f(rq & 0xffffu), to = bf2f(rq >> 16);
      uint32_t outv = (uint32_t)f2bf(te * c - to * sn) | ((uint32_t)f2bf(te * sn + to * c) << 16);
      *(uint32_t*)(qr + (size_t)s * DMODEL + colq) = outv;
    }
    {
      float te = bf2f(rk & 0xffffu), to = bf2f(rk >> 16);
      uint32_t outv = (uint32_t)f2bf(te * c - to * sn) | ((uint32_t)f2bf(te * sn + to * c) << 16);
      *(uint32_t*)(kr + (size_t)s * DMODEL + colq) = outv;
    }
  }
#pragma unroll
  for (int i = 0; i < 16; ++i) {
    int e = i * 256 + t;
    int sl = e >> 6, d = e & 63;
    tl[sl][d] = qkv[(size_t)(sb + sl) * 3 * DMODEL + 2 * DMODEL + hh * DHEAD + d];
  }
  __syncthreads();
#pragma unroll
  for (int i = 0; i < 16; ++i) {
    int e = i * 256 + t;
    int d = e >> 6, sl = e & 63;
    vT[(size_t)(hh * DHEAD + d) * S_LEN + sb + sl] = tl[sl][d];
  }
}

// ---------------------------------------------------------------------------
// GEMM v8 (kept from r17, now isolated): counted-vmcnt 2-deep pipeline with
// inline-asm ds_read_b128 (invisible to compiler dep-tracking, so no auto
// vmcnt(0) drain before the fragment reads) + explicit lgkmcnt(0) +
// sched_barrier(0) before MFMA (rule #18).
// EPI 0: bias -> bf16.  EPI 2: gelu(bias) -> bf16.  EPI 3: raw fp32 partial.
// ---------------------------------------------------------------------------
template <int EPI, int BM>
__global__ __launch_bounds__(256) void k_gemm2(const bf16* __restrict__ A,
                                               const bf16* __restrict__ BT,
                                               const float* __restrict__ bias,
                                               void* __restrict__ out,
                                               int M, int N, int K, int Kc) {
  constexpr int MF = BM / 32;  // m-frags per wave
  __shared__ bf16 As[2][BM * 64];
  __shared__ bf16 Bs[2][128 * 64];
  int t = threadIdx.x;
  int w = t >> 6, l = t & 63, lr = l & 15, lg = l >> 4;

  int nxy = gridDim.x * gridDim.y;
  int bid = blockIdx.y * gridDim.x + blockIdx.x;
  int chk8 = nxy >> 3;
  int swz = (bid & 7) * chk8 + (bid >> 3);
  int bx = swz % gridDim.x, by = swz / gridDim.x;
  int bm = bx * BM, bn = by * 128;
  int k0 = blockIdx.z * Kc;
  int wm = (w >> 1) * (BM / 2), wn = (w & 1) * 64;

  f32x4 zero4 = {0.f, 0.f, 0.f, 0.f};
  f32x4 acc[MF][4];
#pragma unroll
  for (int mf = 0; mf < MF; ++mf)
#pragma unroll
    for (int nf = 0; nf < 4; ++nf) acc[mf][nf] = zero4;

  auto stage = [&](int buf, int kk) {
#pragma unroll
    for (int i = 0; i < BM / 32; ++i) {
      int chunk = i * 256 + t;
      int row = chunk >> 3;
      int scol = ((chunk ^ row) & 7) << 3;
      __builtin_amdgcn_global_load_lds(
          (__attribute__((address_space(1))) void*)(A + (size_t)(bm + row) * K + kk + scol),
          (__attribute__((address_space(3))) void*)(&As[buf][chunk * 8]), 16, 0, 0);
    }
#pragma unroll
    for (int i = 0; i < 4; ++i) {
      int chunk = i * 256 + t;
      int row = chunk >> 3;
      int scol = ((chunk ^ row) & 7) << 3;
      __builtin_amdgcn_global_load_lds(
          (__attribute__((address_space(1))) void*)(BT + (size_t)(bn + row) * K + kk + scol),
          (__attribute__((address_space(3))) void*)(&Bs[buf][chunk * 8]), 16, 0, 0);
    }
  };

  // per-lane LDS byte addresses of the fragment slots
  uint32_t aoff[MF], boff[4];
#pragma unroll
  for (int mf = 0; mf < MF; ++mf) {
    int row = wm + mf * 16 + lr;
    aoff[mf] = (uint32_t)(row * 64 + ((lg ^ (row & 7)) << 3)) * 2;
  }
#pragma unroll
  for (int nf = 0; nf < 4; ++nf) {
    int row = wn + nf * 16 + lr;
    boff[nf] = (uint32_t)(row * 64 + ((lg ^ (row & 7)) << 3)) * 2;
  }
  // h=1 flips bit2 of the slot index: addr ^= (4<<3)*2 = 64 bytes
  uint32_t abase0 = (uint32_t)(uintptr_t)&As[0][0];
  uint32_t bbase0 = (uint32_t)(uintptr_t)&Bs[0][0];
  constexpr uint32_t ABUF = (uint32_t)(BM * 64 * 2);
  constexpr uint32_t BBUF = (uint32_t)(128 * 64 * 2);

  int nt = Kc / 64;
  stage(0, k0);
  stage(1, k0 + 64);  // 2 tiles in flight
  int cur = 0;
  for (int kt = 0; kt < nt; ++kt) {
    // wait for the OLDEST stage (tile kt) only; tile kt+1 stays in flight
    if (kt + 1 < nt) {
      if constexpr (BM == 128)
        asm volatile("s_waitcnt vmcnt(8)" ::: "memory");
      else
        asm volatile("s_waitcnt vmcnt(6)" ::: "memory");
    } else {
      asm volatile("s_waitcnt vmcnt(0)" ::: "memory");
    }
    __builtin_amdgcn_s_barrier();  // all waves' tile-kt loads landed
    __builtin_amdgcn_sched_barrier(0);
    // asm ds_read: invisible to compiler dep-tracking -> no auto vmcnt(0)
    bf16x8 af[2][MF], bfr[2][4];
    {
      uint32_t ab = abase0 + (cur ? ABUF : 0u);
      uint32_t bb = bbase0 + (cur ? BBUF : 0u);
#pragma unroll
      for (int h = 0; h < 2; ++h) {
#pragma unroll
        for (int mf = 0; mf < MF; ++mf) {
          uint32_t ad = ab + (aoff[mf] ^ (h ? 64u : 0u));
          asm volatile("ds_read_b128 %0, %1" : "=v"(af[h][mf]) : "v"(ad));
        }
#pragma unroll
        for (int nf = 0; nf < 4; ++nf) {
          uint32_t bd = bb + (boff[nf] ^ (h ? 64u : 0u));
          asm volatile("ds_read_b128 %0, %1" : "=v"(bfr[h][nf]) : "v"(bd));
        }
      }
    }
    asm volatile("s_waitcnt lgkmcnt(0)" ::: "memory");
    __builtin_amdgcn_sched_barrier(0);  // rule #18: pin MFMA after lgkm wait
    __builtin_amdgcn_s_barrier();       // all waves done reading buf[cur]
    if (kt + 2 < nt) stage(cur, k0 + (kt + 2) * 64);  // refill freed buffer
    __builtin_amdgcn_sched_barrier(0);
#pragma unroll
    for (int h = 0; h < 2; ++h)
#pragma unroll
      for (int mf = 0; mf < MF; ++mf)
#pragma unroll
        for (int nf = 0; nf < 4; ++nf)
          acc[mf][nf] = MFMA16x16(af[h][mf], bfr[h][nf], acc[mf][nf]);
    cur ^= 1;
  }

  if (EPI == 3) {
    float* outf = (float*)out + (size_t)blockIdx.z * ((size_t)M * N);
#pragma unroll
    for (int mf = 0; mf < MF; ++mf)
#pragma unroll
      for (int nf = 0; nf < 4; ++nf) {
        int col = bn + wn + nf * 16 + lr;
        int row0 = bm + wm + mf * 16 + lg * 4;
#pragma unroll
        for (int r = 0; r < 4; ++r)
          outf[(size_t)(row0 + r) * N + col] = acc[mf][nf][r];
      }
  } else {
    bf16* outb = (bf16*)out;
#pragma unroll
    for (int mf = 0; mf < MF; ++mf)
#pragma unroll
      for (int nf = 0; nf < 4; ++nf) {
        int col = bn + wn + nf * 16 + lr;
        float bv = bias[col];
        int row0 = bm + wm + mf * 16 + lg * 4;
#pragma unroll
        for (int r = 0; r < 4; ++r) {
          float v = acc[mf][nf][r] + bv;
          if (EPI == 2)
            v = 0.5f * v * (1.0f + tanhf(0.7978845608028654f * (v + 0.044715f * v * v * v)));
          outb[(size_t)(row0 + r) * N + col] = __float2bfloat16(v);
        }
      }
  }
}

// ---------------------------------------------------------------------------
// Flash attention v7 (r15/r16-exact revert — 70.4us, WRITE 4MB stable over
// 3 rounds; r17's wave-uniform fast-path branch spilled: WRITE 334MB, 150us.
// Lesson x4: this body is at the VGPR cliff; NO added control flow.)
// ---------------------------------------------------------------------------
#define ATTN_TILE(KC0, KC1, KC2, KC3, KN0, KN1, KN2, KN3, IT)                  \
  {                                                                            \
    const int j0 = jbase + (IT) * 32;                                          \
    f32x16 sC;                                                                 \
    _Pragma("unroll") for (int r = 0; r < 16; ++r) sC[r] = 0.f;                \
    __builtin_amdgcn_s_setprio(1);                                             \
    sC = MFMA32x32(KC0, qf0, sC);                                              \
    sC = MFMA32x32(KC1, qf1, sC);                                              \
    sC = MFMA32x32(KC2, qf2, sC);                                              \
    sC = MFMA32x32(KC3, qf3, sC);                                              \
    __builtin_amdgcn_s_setprio(0);                                             \
    const bf16* vbase = vrow + j0;                                             \
    bf16x8 va00 = *(const bf16x8*)(vbase);                                     \
    bf16x8 va01 = *(const bf16x8*)(vbase + 16);                                \
    bf16x8 va10 = *(const bf16x8*)(vbase + 32 * S_LEN);                        \
    bf16x8 va11 = *(const bf16x8*)(vbase + 32 * S_LEN + 16);                   \
    {                                                                          \
      int jn = j0 + 32;                                                        \
      int jmax = jbase + 480;                                                  \
      jn = (jn > jmax) ? jmax : jn;                                            \
      const bf16* kn = krow + (size_t)jn * DMODEL;                             \
      KN0 = *(const bf16x8*)(kn);                                              \
      KN1 = *(const bf16x8*)(kn + 16);                                         \
      KN2 = *(const bf16x8*)(kn + 32);                                         \
      KN3 = *(const bf16x8*)(kn + 48);                                         \
    }                                                                          \
    int tt = j0 + hi * 4 - sl0;                                                \
    _Pragma("unroll") for (int r = 0; r < 16; ++r) {                           \
      int ku = tt + ((r & 3) + 8 * (r >> 2));                                  \
      float fb = ((uint32_t)ku < spanu) ? LOG2E : 0.0f;                        \
      sC[r] = sC[r] * C1 + fb;                                                 \
    }                                                                          \
    float rm = sC[0];                                                          \
    _Pragma("unroll") for (int r = 1; r < 16; ++r) rm = fmaxf(rm, sC[r]);      \
    uint32_t ra = __builtin_bit_cast(uint32_t, rm), rb = ra;                   \
    pl32swap(ra, rb);                                                          \
    float rmax =                                                               \
        fmaxf(__builtin_bit_cast(float, ra), __builtin_bit_cast(float, rb));   \
    if (__any(rmax > m_r + 8.0f)) {                                            \
      float mn = fmaxf(m_r, rmax);                                             \
      float fs = EXP2(m_r - mn);                                               \
      m_r = mn;                                                                \
      l_r *= fs;                                                               \
      _Pragma("unroll") for (int r = 0; r < 16; ++r) {                         \
        oC0[r] *= fs;                                                          \
        oC1[r] *= fs;                                                          \
      }                                                                        \
    }                                                                          \
    _Pragma("unroll") for (int r = 0; r < 16; ++r) {                           \
      float pv = EXP2(sC[r] - m_r);                                            \
      sC[r] = pv;                                                              \
      l_r += pv;                                                               \
    }                                                                          \
    uint32_t u0 = cvtpk(sC[0], sC[1]), u1 = cvtpk(sC[2], sC[3]);               \
    uint32_t u2 = cvtpk(sC[4], sC[5]), u3 = cvtpk(sC[6], sC[7]);               \
    uint32_t u4 = cvtpk(sC[8], sC[9]), u5 = cvtpk(sC[10], sC[11]);             \
    uint32_t u6 = cvtpk(sC[12], sC[13]), u7 = cvtpk(sC[14], sC[15]);           \
    pl32swap(u0, u2);                                                          \
    pl32swap(u1, u3);                                                          \
    pl32swap(u4, u6);                                                          \
    pl32swap(u5, u7);                                                          \
    i32x4 pi0 = {(int)u0, (int)u1, (int)u2, (int)u3};                          \
    i32x4 pi1 = {(int)u4, (int)u5, (int)u6, (int)u7};                          \
    bf16x8 pb0 = __builtin_bit_cast(bf16x8, pi0);                              \
    bf16x8 pb1 = __builtin_bit_cast(bf16x8, pi1);                              \
    __builtin_amdgcn_s_setprio(1);                                             \
    oC0 = MFMA32x32(va00, pb0, oC0);                                           \
    oC0 = MFMA32x32(va01, pb1, oC0);                                           \
    oC1 = MFMA32x32(va10, pb0, oC1);                                           \
    oC1 = MFMA32x32(va11, pb1, oC1);                                           \
    __builtin_amdgcn_s_setprio(0);                                             \
  }

__global__ __launch_bounds__(256, 4) void k_attn(const bf16* __restrict__ qr,
                                                 const bf16* __restrict__ kr,
                                                 const bf16* __restrict__ vT,
                                                 const int* __restrict__ offs,
                                                 bf16* __restrict__ ao) {
  __shared__ float oO[4][64][33];
  __shared__ float mM[4][32];
  __shared__ float lL[4][32];

  int t = threadIdx.x, w = t >> 6, l = t & 63;
  int ql = l & 31, hi = l >> 5, hi8 = hi * 8;
  int hh = blockIdx.x, qb = blockIdx.y * 32;
  int h64 = hh * DHEAD;

  constexpr float LOG2E = 1.4426950408889634f;
  constexpr float C1 = 0.125f * LOG2E;

  int q = qb + ql;
  int o0 = offs[0], o1 = offs[1], o2 = offs[2], o3 = offs[3], o4 = offs[4];
  int sl0 = -1073741824, sh0 = 1073741824;
  sl0 = (o0 <= q) ? o0 : sl0;
  sl0 = (o1 <= q) ? o1 : sl0;
  sl0 = (o2 <= q) ? o2 : sl0;
  sl0 = (o3 <= q) ? o3 : sl0;
  sl0 = (o4 <= q) ? o4 : sl0;
  sh0 = (o4 > q) ? o4 : sh0;
  sh0 = (o3 > q) ? o3 : sh0;
  sh0 = (o2 > q) ? o2 : sh0;
  sh0 = (o1 > q) ? o1 : sh0;
  sh0 = (o0 > q) ? o0 : sh0;
  uint32_t spanu = (uint32_t)(sh0 - sl0);

  const bf16* qbase = qr + (size_t)q * DMODEL + h64 + hi8;
  bf16x8 qf0 = *(const bf16x8*)(qbase);
  bf16x8 qf1 = *(const bf16x8*)(qbase + 16);
  bf16x8 qf2 = *(const bf16x8*)(qbase + 32);
  bf16x8 qf3 = *(const bf16x8*)(qbase + 48);

  f32x16 oC0, oC1;
#pragma unroll
  for (int r = 0; r < 16; ++r) { oC0[r] = 0.f; oC1[r] = 0.f; }
  float m_r = -1e30f, l_r = 0.f;

  const bf16* vrow = vT + (size_t)(h64 + ql) * S_LEN + hi8;
  const bf16* krow = kr + (size_t)ql * DMODEL + h64 + hi8;
  int jbase = w * 512;

  bf16x8 kA0, kA1, kA2, kA3, kB0, kB1, kB2, kB3;
  {
    const bf16* kb = krow + (size_t)jbase * DMODEL;
    kA0 = *(const bf16x8*)(kb);
    kA1 = *(const bf16x8*)(kb + 16);
    kA2 = *(const bf16x8*)(kb + 32);
    kA3 = *(const bf16x8*)(kb + 48);
  }

  for (int itp = 0; itp < 8; ++itp) {
    ATTN_TILE(kA0, kA1, kA2, kA3, kB0, kB1, kB2, kB3, itp * 2);
    ATTN_TILE(kB0, kB1, kB2, kB3, kA0, kA1, kA2, kA3, itp * 2 + 1);
  }

  {
    uint32_t la = __builtin_bit_cast(uint32_t, l_r), lb = la;
    pl32swap(la, lb);
    l_r = __builtin_bit_cast(float, la) + __builtin_bit_cast(float, lb);
  }
  if (hi == 0) {
    mM[w][ql] = m_r;
    lL[w][ql] = l_r;
  }
#pragma unroll
  for (int r = 0; r < 16; ++r) {
    int d = (r & 3) + 8 * (r >> 2) + 4 * hi;
    oO[w][d][ql] = oC0[r];
    oO[w][d + 32][ql] = oC1[r];
  }
  __syncthreads();

  {
    int mq = t & 31, dbse = (t >> 5) * 8;
    float m0 = mM[0][mq], m1 = mM[1][mq], m2 = mM[2][mq], m3 = mM[3][mq];
    float ms = fmaxf(fmaxf(m0, m1), fmaxf(m2, m3));
    float a0 = EXP2(m0 - ms), a1 = EXP2(m1 - ms), a2 = EXP2(m2 - ms), a3 = EXP2(m3 - ms);
    float ll = a0 * lL[0][mq] + a1 * lL[1][mq] + a2 * lL[2][mq] + a3 * lL[3][mq];
    float inv = 1.0f / ll;
    uint4 pkv;
    uint32_t pw[4];
#pragma unroll
    for (int i = 0; i < 4; ++i) {
      int d0 = dbse + 2 * i, d1 = dbse + 2 * i + 1;
      float e0 = (a0 * oO[0][d0][mq] + a1 * oO[1][d0][mq] + a2 * oO[2][d0][mq] +
                  a3 * oO[3][d0][mq]) * inv;
      float e1 = (a0 * oO[0][d1][mq] + a1 * oO[1][d1][mq] + a2 * oO[2][d1][mq] +
                  a3 * oO[3][d1][mq]) * inv;
      pw[i] = (uint32_t)f2bf(e0) | ((uint32_t)f2bf(e1) << 16);
    }
    pkv.x = pw[0]; pkv.y = pw[1]; pkv.z = pw[2]; pkv.w = pw[3];
    *(uint4*)(ao + (size_t)(qb + mq) * DMODEL + h64 + dbse) = pkv;
  }
}

// ---------------------------------------------------------------------------
extern "C" void kernel_launch(void* const* d_in, const int* in_sizes, int n_in,
                              void* d_out, int out_size, void* d_ws, size_t ws_size,
                              hipStream_t stream) {
  const float* x = (const float*)d_in[0];
  const int* offs = (const int*)d_in[1];
  const float* fcos = (const float*)d_in[2];
  const float* fsin = (const float*)d_in[3];
  const float* ln0g = (const float*)d_in[4];
  const float* ln0b = (const float*)d_in[5];
  const float* ln1g = (const float*)d_in[6];
  const float* ln1b = (const float*)d_in[7];
  const float* wqkv = (const float*)d_in[8];
  const float* bqkv = (const float*)d_in[9];
  const float* wo = (const float*)d_in[10];
  const float* bo = (const float*)d_in[11];
  const float* wu = (const float*)d_in[12];
  const float* bu = (const float*)d_in[13];
  const float* wd = (const float*)d_in[14];
  const float* bd = (const float*)d_in[15];
  const float* lnfg = (const float*)d_in[16];
  const float* lnfb = (const float*)d_in[17];

  char* ws = (char*)d_ws;
  size_t off = 0;
  auto alloc = [&](size_t bytes) -> void* {
    void* p = ws + off;
    off += (bytes + 255) & ~(size_t)255;
    return p;
  };
  bf16* wqkvT = (bf16*)alloc((size_t)NLAYER * 3 * DMODEL * DMODEL * 2);
  bf16* woT = (bf16*)alloc((size_t)NLAYER * DMODEL * DMODEL * 2);
  bf16* wuT = (bf16*)alloc((size_t)NLAYER * DMODEL * FFDIM * 2);
  bf16* wdT = (bf16*)alloc((size_t)NLAYER * FFDIM * DMODEL * 2);
  float* hbuf = (float*)alloc((size_t)S_LEN * DMODEL * 4);
  bf16* ybuf = (bf16*)alloc((size_t)S_LEN * DMODEL * 2);   // partDN head space
  bf16* qkv = (bf16*)alloc((size_t)S_LEN * 3 * DMODEL * 2);
  bf16* qrb = (bf16*)alloc((size_t)S_LEN * DMODEL * 2);
  bf16* krb = (bf16*)alloc((size_t)S_LEN * DMODEL * 2);
  bf16* vTb = (bf16*)alloc((size_t)S_LEN * DMODEL * 2);
  bf16* aob = (bf16*)alloc((size_t)S_LEN * DMODEL * 2);
  bf16* midb = (bf16*)alloc((size_t)S_LEN * FFDIM * 2);
  bf16* ybuf2 = (bf16*)alloc((size_t)S_LEN * DMODEL * 2);  // LN outputs (A operand)

  float* partWO = (float*)qkv;
  float* partDN = (float*)ybuf;

  for (int ly = 0; ly < NLAYER; ++ly) {
    k_tcast<<<dim3(3 * DMODEL / 32, DMODEL / 32), 256, 0, stream>>>(
        wqkv + (size_t)ly * DMODEL * 3 * DMODEL, wqkvT + (size_t)ly * 3 * DMODEL * DMODEL, DMODEL, 3 * DMODEL);
    k_tcast<<<dim3(DMODEL / 32, DMODEL / 32), 256, 0, stream>>>(
        wo + (size_t)ly * DMODEL * DMODEL, woT + (size_t)ly * DMODEL * DMODEL, DMODEL, DMODEL);
    k_tcast<<<dim3(FFDIM / 32, DMODEL / 32), 256, 0, stream>>>(
        wu + (size_t)ly * DMODEL * FFDIM, wuT + (size_t)ly * DMODEL * FFDIM, DMODEL, FFDIM);
    k_tcast<<<dim3(DMODEL / 32, FFDIM / 32), 256, 0, stream>>>(
        wd + (size_t)ly * FFDIM * DMODEL, wdT + (size_t)ly * FFDIM * DMODEL, FFDIM, DMODEL);
  }
  hipMemcpyAsync(hbuf, x, (size_t)S_LEN * DMODEL * 4, hipMemcpyDeviceToDevice, stream);

  k_ln<bf16><<<S_LEN, 256, 0, stream>>>(hbuf, ln0g, ln0b, ybuf2);

  for (int ly = 0; ly < NLAYER; ++ly) {
    // QKV: M=2048, N=3072, K=1024  (grid 16x24 = 384)
    k_gemm2<0, 128><<<dim3(S_LEN / 128, 3 * DMODEL / 128, 1), 256, 0, stream>>>(
        ybuf2, wqkvT + (size_t)ly * 3 * DMODEL * DMODEL, bqkv + ly * 3 * DMODEL, qkv,
        S_LEN, 3 * DMODEL, DMODEL, DMODEL);
    k_ropetv<<<dim3(S_LEN / 64, NHEAD), 256, 0, stream>>>(qkv, fcos, fsin, qrb, krb, vTb);
    k_attn<<<dim3(NHEAD, S_LEN / 32), 256, 0, stream>>>(qrb, krb, vTb, offs, aob);
    // WO: M=2048, N=1024, K=1024, split-K 2, BM=64  (xy grid 32x8 = 256)
    k_gemm2<3, 64><<<dim3(S_LEN / 64, DMODEL / 128, 2), 256, 0, stream>>>(
        aob, woT + (size_t)ly * DMODEL * DMODEL, nullptr, partWO,
        S_LEN, DMODEL, DMODEL, DMODEL / 2);
    k_redln<2, bf16><<<S_LEN, 256, 0, stream>>>(
        partWO, bo + ly * DMODEL, hbuf, ln1g + ly * DMODEL, ln1b + ly * DMODEL, ybuf2);
    // UP: M=2048, N=4096, K=1024  (grid 16x32 = 512)
    k_gemm2<2, 128><<<dim3(S_LEN / 128, FFDIM / 128, 1), 256, 0, stream>>>(
        ybuf2, wuT + (size_t)ly * DMODEL * FFDIM, bu + ly * FFDIM, midb,
        S_LEN, FFDIM, DMODEL, DMODEL);
    // DOWN: M=2048, N=1024, K=4096, split-K 4, BM=128  (xy grid 16x8 = 128)
    k_gemm2<3, 128><<<dim3(S_LEN / 128, DMODEL / 128, 4), 256, 0, stream>>>(
        midb, wdT + (size_t)ly * FFDIM * DMODEL, nullptr, partDN,
        S_LEN, DMODEL, FFDIM, FFDIM / 4);
    if (ly + 1 < NLAYER) {
      k_redln<4, bf16><<<S_LEN, 256, 0, stream>>>(
          partDN, bd + ly * DMODEL, hbuf, ln0g + (ly + 1) * DMODEL,
          ln0b + (ly + 1) * DMODEL, ybuf2);
    } else {
      k_redln<4, float><<<S_LEN, 256, 0, stream>>>(
          partDN, bd + ly * DMODEL, hbuf, lnfg, lnfb, (float*)d_out);
    }
  }
}

// Round 19
// 386.000 us; speedup vs baseline: 1.5108x; 1.0398x over previous
//
#include <hip/hip_runtime.h>
#include <hip/hip_bf16.h>
#include <stdint.h>
#include <math.h>

#define S_LEN 2048
#define DMODEL 1024
#define NHEAD 16
#define DHEAD 64
#define FFDIM 4096
#define NLAYER 2

using bf16 = __hip_bfloat16;
typedef __attribute__((ext_vector_type(8))) short bf16x8;
typedef __attribute__((ext_vector_type(4))) float f32x4;
typedef __attribute__((ext_vector_type(16))) float f32x16;
typedef __attribute__((ext_vector_type(4))) int i32x4;

#define MFMA16x16(A, B, C) __builtin_amdgcn_mfma_f32_16x16x32_bf16(A, B, C, 0, 0, 0)
#define MFMA32x32(A, B, C) __builtin_amdgcn_mfma_f32_32x32x16_bf16(A, B, C, 0, 0, 0)
#define EXP2(x) __builtin_amdgcn_exp2f(x)

__device__ __forceinline__ float bf2f(uint32_t u16bits) {
  union { uint32_t i; float f; } x;
  x.i = u16bits << 16;
  return x.f;
}
__device__ __forceinline__ uint16_t f2bf(float f) {
  return __builtin_bit_cast(uint16_t, __float2bfloat16(f));
}

// v_cvt_pk_bf16_f32: pack two f32 -> one dword of 2 bf16 (no builtin on gfx950)
__device__ __forceinline__ uint32_t cvtpk(float lo, float hi) {
  uint32_t r;
  asm("v_cvt_pk_bf16_f32 %0, %1, %2" : "=v"(r) : "v"(lo), "v"(hi));
  return r;
}
// v_permlane32_swap_b32
__device__ __forceinline__ void pl32swap(uint32_t& a, uint32_t& b) {
#if __has_builtin(__builtin_amdgcn_permlane32_swap)
  typedef __attribute__((ext_vector_type(2))) int i32x2;
  i32x2 r = __builtin_amdgcn_permlane32_swap((int)a, (int)b, false, false);
  a = (uint32_t)r.x;
  b = (uint32_t)r.y;
#else
  asm volatile("v_permlane32_swap_b32 %0, %1" : "+v"(a), "+v"(b));
#endif
}

// ---------------------------------------------------------------------------
// Weight cast + transpose: in fp32 (R x C)  ->  out bf16 (C x R)
// ---------------------------------------------------------------------------
__global__ __launch_bounds__(256) void k_tcast(const float* __restrict__ in,
                                               bf16* __restrict__ out,
                                               int R, int C) {
  __shared__ float tl[32][33];
  int t = threadIdx.x;
  int r0 = blockIdx.y * 32, c0 = blockIdx.x * 32;
  int cl = t & 31, rl = t >> 5;
#pragma unroll
  for (int i = 0; i < 4; ++i)
    tl[rl + i * 8][cl] = in[(size_t)(r0 + rl + i * 8) * C + c0 + cl];
  __syncthreads();
#pragma unroll
  for (int i = 0; i < 4; ++i)
    out[(size_t)(c0 + rl + i * 8) * R + r0 + cl] = __float2bfloat16(tl[cl][rl + i * 8]);
}

// ---------------------------------------------------------------------------
// LayerNorm helpers
// ---------------------------------------------------------------------------
__device__ __forceinline__ void ln_store4(bf16* p, float a, float b, float c, float d) {
  uint2 u;
  u.x = (uint32_t)f2bf(a) | ((uint32_t)f2bf(b) << 16);
  u.y = (uint32_t)f2bf(c) | ((uint32_t)f2bf(d) << 16);
  *(uint2*)p = u;
}
__device__ __forceinline__ void ln_store4(float* p, float a, float b, float c, float d) {
  *(float4*)p = make_float4(a, b, c, d);
}

// row-wide (1024) LN from 4 per-thread values; block = 256 threads
template <typename OUT>
__device__ __forceinline__ void ln_rowcore(float v0, float v1, float v2, float v3,
                                           const float* __restrict__ g,
                                           const float* __restrict__ b,
                                           OUT* __restrict__ yrow, int t) {
  float s = v0 + v1 + v2 + v3;
  float s2 = v0 * v0 + v1 * v1 + v2 * v2 + v3 * v3;
#pragma unroll
  for (int off = 32; off > 0; off >>= 1) {
    s += __shfl_down(s, off);
    s2 += __shfl_down(s2, off);
  }
  __shared__ float red[8];
  int w = t >> 6;
  if ((t & 63) == 0) { red[w] = s; red[4 + w] = s2; }
  __syncthreads();
  s = red[0] + red[1] + red[2] + red[3];
  s2 = red[4] + red[5] + red[6] + red[7];
  float mean = s * (1.0f / DMODEL);
  float var = s2 * (1.0f / DMODEL) - mean * mean;
  float rstd = rsqrtf(var + 1e-5f);
  float4 gv = ((const float4*)g)[t];
  float4 bv = ((const float4*)b)[t];
  ln_store4(yrow + t * 4, (v0 - mean) * rstd * gv.x + bv.x,
            (v1 - mean) * rstd * gv.y + bv.y, (v2 - mean) * rstd * gv.z + bv.z,
            (v3 - mean) * rstd * gv.w + bv.w);
}

template <typename OUT>
__global__ __launch_bounds__(256) void k_ln(const float* __restrict__ h,
                                            const float* __restrict__ g,
                                            const float* __restrict__ b,
                                            OUT* __restrict__ y) {
  int row = blockIdx.x, t = threadIdx.x;
  const float4 v = ((const float4*)(h + (size_t)row * DMODEL))[t];
  ln_rowcore<OUT>(v.x, v.y, v.z, v.w, g, b, y + (size_t)row * DMODEL, t);
}

// ---------------------------------------------------------------------------
// Fused split-K merge + residual + LayerNorm:
//   hnew = hb + bias + sum_ks part[ks];  hb := hnew;  y := LN(hnew; g,b)
// ---------------------------------------------------------------------------
template <int KS, typename OUT>
__global__ __launch_bounds__(256) void k_redln(const float* __restrict__ part,
                                               const float* __restrict__ bias,
                                               float* __restrict__ hb,
                                               const float* __restrict__ g,
                                               const float* __restrict__ b,
                                               OUT* __restrict__ y) {
  int row = blockIdx.x, t = threadIdx.x;
  size_t base = (size_t)row * DMODEL + t * 4;
  float4 r = *(const float4*)(hb + base);
  float4 bv = *(const float4*)(bias + t * 4);
  float v0 = r.x + bv.x, v1 = r.y + bv.y, v2 = r.z + bv.z, v3 = r.w + bv.w;
#pragma unroll
  for (int ks = 0; ks < KS; ++ks) {
    float4 p = *(const float4*)(part + (size_t)ks * (S_LEN * DMODEL) + base);
    v0 += p.x; v1 += p.y; v2 += p.z; v3 += p.w;
  }
  *(float4*)(hb + base) = make_float4(v0, v1, v2, v3);
  ln_rowcore<OUT>(v0, v1, v2, v3, g, b, y + (size_t)row * DMODEL, t);
}

// ---------------------------------------------------------------------------
// Fused RoPE (q,k) + V transpose. Grid (S/64, NHEAD), 256 threads.
// ---------------------------------------------------------------------------
__global__ __launch_bounds__(256) void k_ropetv(const bf16* __restrict__ qkv,
                                                const float* __restrict__ fcos,
                                                const float* __restrict__ fsin,
                                                bf16* __restrict__ qr,
                                                bf16* __restrict__ kr,
                                                bf16* __restrict__ vT) {
  __shared__ bf16 tl[64][65];
  int t = threadIdx.x;
  int hh = blockIdx.y;
  int sb = blockIdx.x * 64;
#pragma unroll
  for (int i = 0; i < 8; ++i) {
    int e = i * 256 + t;
    int p = e & 31, sl = e >> 5;
    int s = sb + sl;
    float c = fcos[s * 32 + p], sn = fsin[s * 32 + p];
    int colq = hh * DHEAD + 2 * p;
    uint32_t rq = *(const uint32_t*)(qkv + (size_t)s * 3 * DMODEL + colq);
    uint32_t rk = *(const uint32_t*)(qkv + (size_t)s * 3 * DMODEL + DMODEL + colq);
    {
      float te = bf2f(rq & 0xffffu), to = bf2f(rq >> 16);
      uint32_t outv = (uint32_t)f2bf(te * c - to * sn) | ((uint32_t)f2bf(te * sn + to * c) << 16);
      *(uint32_t*)(qr + (size_t)s * DMODEL + colq) = outv;
    }
    {
      float te = bf2f(rk & 0xffffu), to = bf2f(rk >> 16);
      uint32_t outv = (uint32_t)f2bf(te * c - to * sn) | ((uint32_t)f2bf(te * sn + to * c) << 16);
      *(uint32_t*)(kr + (size_t)s * DMODEL + colq) = outv;
    }
  }
#pragma unroll
  for (int i = 0; i < 16; ++i) {
    int e = i * 256 + t;
    int sl = e >> 6, d = e & 63;
    tl[sl][d] = qkv[(size_t)(sb + sl) * 3 * DMODEL + 2 * DMODEL + hh * DHEAD + d];
  }
  __syncthreads();
#pragma unroll
  for (int i = 0; i < 16; ++i) {
    int e = i * 256 + t;
    int d = e >> 6, sl = e & 63;
    vT[(size_t)(hh * DHEAD + d) * S_LEN + sb + sl] = tl[sl][d];
  }
}

// ---------------------------------------------------------------------------
// GEMM (session-best r15 config): BM x 128 tile, BK=64, T2 XOR swizzle,
// T1 XCD swizzle, split-K via z, counted-vmcnt 2-deep prefetch with raw
// s_barrier + HIP ds_reads. Measured 387us total; asm-ds_read (r16/r17)
// and all other pipeline variants were neutral-to-worse — the remaining
// stall is the barrier handshake floor at 2 blocks/CU (latency-bound local
// minimum of this decomposition, not a memory/compute roofline).
// EPI 0: bias -> bf16.  EPI 2: gelu(bias) -> bf16.  EPI 3: raw fp32 partial.
// ---------------------------------------------------------------------------
template <int EPI, int BM>
__global__ __launch_bounds__(256) void k_gemm2(const bf16* __restrict__ A,
                                               const bf16* __restrict__ BT,
                                               const float* __restrict__ bias,
                                               void* __restrict__ out,
                                               int M, int N, int K, int Kc) {
  constexpr int MF = BM / 32;  // m-frags per wave
  __shared__ bf16 As[2][BM * 64];
  __shared__ bf16 Bs[2][128 * 64];
  int t = threadIdx.x;
  int w = t >> 6, l = t & 63, lr = l & 15, lg = l >> 4;

  int nxy = gridDim.x * gridDim.y;
  int bid = blockIdx.y * gridDim.x + blockIdx.x;
  int chk8 = nxy >> 3;
  int swz = (bid & 7) * chk8 + (bid >> 3);
  int bx = swz % gridDim.x, by = swz / gridDim.x;
  int bm = bx * BM, bn = by * 128;
  int k0 = blockIdx.z * Kc;
  int wm = (w >> 1) * (BM / 2), wn = (w & 1) * 64;

  f32x4 zero4 = {0.f, 0.f, 0.f, 0.f};
  f32x4 acc[MF][4];
#pragma unroll
  for (int mf = 0; mf < MF; ++mf)
#pragma unroll
    for (int nf = 0; nf < 4; ++nf) acc[mf][nf] = zero4;

  auto stage = [&](int buf, int kk) {
#pragma unroll
    for (int i = 0; i < BM / 32; ++i) {
      int chunk = i * 256 + t;
      int row = chunk >> 3;
      int scol = ((chunk ^ row) & 7) << 3;
      __builtin_amdgcn_global_load_lds(
          (__attribute__((address_space(1))) void*)(A + (size_t)(bm + row) * K + kk + scol),
          (__attribute__((address_space(3))) void*)(&As[buf][chunk * 8]), 16, 0, 0);
    }
#pragma unroll
    for (int i = 0; i < 4; ++i) {
      int chunk = i * 256 + t;
      int row = chunk >> 3;
      int scol = ((chunk ^ row) & 7) << 3;
      __builtin_amdgcn_global_load_lds(
          (__attribute__((address_space(1))) void*)(BT + (size_t)(bn + row) * K + kk + scol),
          (__attribute__((address_space(3))) void*)(&Bs[buf][chunk * 8]), 16, 0, 0);
    }
  };

  int nt = Kc / 64;
  stage(0, k0);
  stage(1, k0 + 64);  // 2 tiles in flight (nt >= 8 for all our shapes)
  int cur = 0;
  for (int kt = 0; kt < nt; ++kt) {
    // wait for the OLDEST stage (tile kt) only; tile kt+1 stays in flight
    if (kt + 1 < nt) {
      if constexpr (BM == 128)
        asm volatile("s_waitcnt vmcnt(8)" ::: "memory");
      else
        asm volatile("s_waitcnt vmcnt(6)" ::: "memory");
    } else {
      asm volatile("s_waitcnt vmcnt(0)" ::: "memory");
    }
    __builtin_amdgcn_s_barrier();  // all waves' tile-kt loads landed
    __builtin_amdgcn_sched_barrier(0);
    bf16x8 af[2][MF], bfr[2][4];
#pragma unroll
    for (int h = 0; h < 2; ++h) {
#pragma unroll
      for (int mf = 0; mf < MF; ++mf) {
        int row = wm + mf * 16 + lr;
        af[h][mf] = *(const bf16x8*)(&As[cur][row * 64 + ((((h << 2) + lg) ^ (row & 7)) << 3)]);
      }
#pragma unroll
      for (int nf = 0; nf < 4; ++nf) {
        int row = wn + nf * 16 + lr;
        bfr[h][nf] = *(const bf16x8*)(&Bs[cur][row * 64 + ((((h << 2) + lg) ^ (row & 7)) << 3)]);
      }
    }
    asm volatile("s_waitcnt lgkmcnt(0)" ::: "memory");
    __builtin_amdgcn_sched_barrier(0);
    __builtin_amdgcn_s_barrier();  // all waves done reading buf[cur]
    if (kt + 2 < nt) stage(cur, k0 + (kt + 2) * 64);  // refill freed buffer
    __builtin_amdgcn_sched_barrier(0);
#pragma unroll
    for (int h = 0; h < 2; ++h)
#pragma unroll
      for (int mf = 0; mf < MF; ++mf)
#pragma unroll
        for (int nf = 0; nf < 4; ++nf)
          acc[mf][nf] = MFMA16x16(af[h][mf], bfr[h][nf], acc[mf][nf]);
    cur ^= 1;
  }

  if (EPI == 3) {
    float* outf = (float*)out + (size_t)blockIdx.z * ((size_t)M * N);
#pragma unroll
    for (int mf = 0; mf < MF; ++mf)
#pragma unroll
      for (int nf = 0; nf < 4; ++nf) {
        int col = bn + wn + nf * 16 + lr;
        int row0 = bm + wm + mf * 16 + lg * 4;
#pragma unroll
        for (int r = 0; r < 4; ++r)
          outf[(size_t)(row0 + r) * N + col] = acc[mf][nf][r];
      }
  } else {
    bf16* outb = (bf16*)out;
#pragma unroll
    for (int mf = 0; mf < MF; ++mf)
#pragma unroll
      for (int nf = 0; nf < 4; ++nf) {
        int col = bn + wn + nf * 16 + lr;
        float bv = bias[col];
        int row0 = bm + wm + mf * 16 + lg * 4;
#pragma unroll
        for (int r = 0; r < 4; ++r) {
          float v = acc[mf][nf][r] + bv;
          if (EPI == 2)
            v = 0.5f * v * (1.0f + tanhf(0.7978845608028654f * (v + 0.044715f * v * v * v)));
          outb[(size_t)(row0 + r) * N + col] = __float2bfloat16(v);
        }
      }
  }
}

// ---------------------------------------------------------------------------
// Flash attention v7 (stable body: 4-wave split-K, swapped-operand 32x32x16,
// in-register softmax via cvt_pk+permlane, defer-max, 2-deep K register
// pipeline with named registers). VGPR-cliff: no added control flow.
// ---------------------------------------------------------------------------
#define ATTN_TILE(KC0, KC1, KC2, KC3, KN0, KN1, KN2, KN3, IT)                  \
  {                                                                            \
    const int j0 = jbase + (IT) * 32;                                          \
    f32x16 sC;                                                                 \
    _Pragma("unroll") for (int r = 0; r < 16; ++r) sC[r] = 0.f;                \
    __builtin_amdgcn_s_setprio(1);                                             \
    sC = MFMA32x32(KC0, qf0, sC);                                              \
    sC = MFMA32x32(KC1, qf1, sC);                                              \
    sC = MFMA32x32(KC2, qf2, sC);                                              \
    sC = MFMA32x32(KC3, qf3, sC);                                              \
    __builtin_amdgcn_s_setprio(0);                                             \
    const bf16* vbase = vrow + j0;                                             \
    bf16x8 va00 = *(const bf16x8*)(vbase);                                     \
    bf16x8 va01 = *(const bf16x8*)(vbase + 16);                                \
    bf16x8 va10 = *(const bf16x8*)(vbase + 32 * S_LEN);                        \
    bf16x8 va11 = *(const bf16x8*)(vbase + 32 * S_LEN + 16);                   \
    {                                                                          \
      int jn = j0 + 32;                                                        \
      int jmax = jbase + 480;                                                  \
      jn = (jn > jmax) ? jmax : jn;                                            \
      const bf16* kn = krow + (size_t)jn * DMODEL;                             \
      KN0 = *(const bf16x8*)(kn);                                              \
      KN1 = *(const bf16x8*)(kn + 16);                                         \
      KN2 = *(const bf16x8*)(kn + 32);                                         \
      KN3 = *(const bf16x8*)(kn + 48);                                         \
    }                                                                          \
    int tt = j0 + hi * 4 - sl0;                                                \
    _Pragma("unroll") for (int r = 0; r < 16; ++r) {                           \
      int ku = tt + ((r & 3) + 8 * (r >> 2));                                  \
      float fb = ((uint32_t)ku < spanu) ? LOG2E : 0.0f;                        \
      sC[r] = sC[r] * C1 + fb;                                                 \
    }                                                                          \
    float rm = sC[0];                                                          \
    _Pragma("unroll") for (int r = 1; r < 16; ++r) rm = fmaxf(rm, sC[r]);      \
    uint32_t ra = __builtin_bit_cast(uint32_t, rm), rb = ra;                   \
    pl32swap(ra, rb);                                                          \
    float rmax =                                                               \
        fmaxf(__builtin_bit_cast(float, ra), __builtin_bit_cast(float, rb));   \
    if (__any(rmax > m_r + 8.0f)) {                                            \
      float mn = fmaxf(m_r, rmax);                                             \
      float fs = EXP2(m_r - mn);                                               \
      m_r = mn;                                                                \
      l_r *= fs;                                                               \
      _Pragma("unroll") for (int r = 0; r < 16; ++r) {                         \
        oC0[r] *= fs;                                                          \
        oC1[r] *= fs;                                                          \
      }                                                                        \
    }                                                                          \
    _Pragma("unroll") for (int r = 0; r < 16; ++r) {                           \
      float pv = EXP2(sC[r] - m_r);                                            \
      sC[r] = pv;                                                              \
      l_r += pv;                                                               \
    }                                                                          \
    uint32_t u0 = cvtpk(sC[0], sC[1]), u1 = cvtpk(sC[2], sC[3]);               \
    uint32_t u2 = cvtpk(sC[4], sC[5]), u3 = cvtpk(sC[6], sC[7]);               \
    uint32_t u4 = cvtpk(sC[8], sC[9]), u5 = cvtpk(sC[10], sC[11]);             \
    uint32_t u6 = cvtpk(sC[12], sC[13]), u7 = cvtpk(sC[14], sC[15]);           \
    pl32swap(u0, u2);                                                          \
    pl32swap(u1, u3);                                                          \
    pl32swap(u4, u6);                                                          \
    pl32swap(u5, u7);                                                          \
    i32x4 pi0 = {(int)u0, (int)u1, (int)u2, (int)u3};                          \
    i32x4 pi1 = {(int)u4, (int)u5, (int)u6, (int)u7};                          \
    bf16x8 pb0 = __builtin_bit_cast(bf16x8, pi0);                              \
    bf16x8 pb1 = __builtin_bit_cast(bf16x8, pi1);                              \
    __builtin_amdgcn_s_setprio(1);                                             \
    oC0 = MFMA32x32(va00, pb0, oC0);                                           \
    oC0 = MFMA32x32(va01, pb1, oC0);                                           \
    oC1 = MFMA32x32(va10, pb0, oC1);                                           \
    oC1 = MFMA32x32(va11, pb1, oC1);                                           \
    __builtin_amdgcn_s_setprio(0);                                             \
  }

__global__ __launch_bounds__(256, 4) void k_attn(const bf16* __restrict__ qr,
                                                 const bf16* __restrict__ kr,
                                                 const bf16* __restrict__ vT,
                                                 const int* __restrict__ offs,
                                                 bf16* __restrict__ ao) {
  __shared__ float oO[4][64][33];
  __shared__ float mM[4][32];
  __shared__ float lL[4][32];

  int t = threadIdx.x, w = t >> 6, l = t & 63;
  int ql = l & 31, hi = l >> 5, hi8 = hi * 8;
  int hh = blockIdx.x, qb = blockIdx.y * 32;
  int h64 = hh * DHEAD;

  constexpr float LOG2E = 1.4426950408889634f;
  constexpr float C1 = 0.125f * LOG2E;

  int q = qb + ql;
  int o0 = offs[0], o1 = offs[1], o2 = offs[2], o3 = offs[3], o4 = offs[4];
  int sl0 = -1073741824, sh0 = 1073741824;
  sl0 = (o0 <= q) ? o0 : sl0;
  sl0 = (o1 <= q) ? o1 : sl0;
  sl0 = (o2 <= q) ? o2 : sl0;
  sl0 = (o3 <= q) ? o3 : sl0;
  sl0 = (o4 <= q) ? o4 : sl0;
  sh0 = (o4 > q) ? o4 : sh0;
  sh0 = (o3 > q) ? o3 : sh0;
  sh0 = (o2 > q) ? o2 : sh0;
  sh0 = (o1 > q) ? o1 : sh0;
  sh0 = (o0 > q) ? o0 : sh0;
  uint32_t spanu = (uint32_t)(sh0 - sl0);

  const bf16* qbase = qr + (size_t)q * DMODEL + h64 + hi8;
  bf16x8 qf0 = *(const bf16x8*)(qbase);
  bf16x8 qf1 = *(const bf16x8*)(qbase + 16);
  bf16x8 qf2 = *(const bf16x8*)(qbase + 32);
  bf16x8 qf3 = *(const bf16x8*)(qbase + 48);

  f32x16 oC0, oC1;
#pragma unroll
  for (int r = 0; r < 16; ++r) { oC0[r] = 0.f; oC1[r] = 0.f; }
  float m_r = -1e30f, l_r = 0.f;

  const bf16* vrow = vT + (size_t)(h64 + ql) * S_LEN + hi8;
  const bf16* krow = kr + (size_t)ql * DMODEL + h64 + hi8;
  int jbase = w * 512;

  bf16x8 kA0, kA1, kA2, kA3, kB0, kB1, kB2, kB3;
  {
    const bf16* kb = krow + (size_t)jbase * DMODEL;
    kA0 = *(const bf16x8*)(kb);
    kA1 = *(const bf16x8*)(kb + 16);
    kA2 = *(const bf16x8*)(kb + 32);
    kA3 = *(const bf16x8*)(kb + 48);
  }

  for (int itp = 0; itp < 8; ++itp) {
    ATTN_TILE(kA0, kA1, kA2, kA3, kB0, kB1, kB2, kB3, itp * 2);
    ATTN_TILE(kB0, kB1, kB2, kB3, kA0, kA1, kA2, kA3, itp * 2 + 1);
  }

  {
    uint32_t la = __builtin_bit_cast(uint32_t, l_r), lb = la;
    pl32swap(la, lb);
    l_r = __builtin_bit_cast(float, la) + __builtin_bit_cast(float, lb);
  }
  if (hi == 0) {
    mM[w][ql] = m_r;
    lL[w][ql] = l_r;
  }
#pragma unroll
  for (int r = 0; r < 16; ++r) {
    int d = (r & 3) + 8 * (r >> 2) + 4 * hi;
    oO[w][d][ql] = oC0[r];
    oO[w][d + 32][ql] = oC1[r];
  }
  __syncthreads();

  {
    int mq = t & 31, dbse = (t >> 5) * 8;
    float m0 = mM[0][mq], m1 = mM[1][mq], m2 = mM[2][mq], m3 = mM[3][mq];
    float ms = fmaxf(fmaxf(m0, m1), fmaxf(m2, m3));
    float a0 = EXP2(m0 - ms), a1 = EXP2(m1 - ms), a2 = EXP2(m2 - ms), a3 = EXP2(m3 - ms);
    float ll = a0 * lL[0][mq] + a1 * lL[1][mq] + a2 * lL[2][mq] + a3 * lL[3][mq];
    float inv = 1.0f / ll;
    uint4 pkv;
    uint32_t pw[4];
#pragma unroll
    for (int i = 0; i < 4; ++i) {
      int d0 = dbse + 2 * i, d1 = dbse + 2 * i + 1;
      float e0 = (a0 * oO[0][d0][mq] + a1 * oO[1][d0][mq] + a2 * oO[2][d0][mq] +
                  a3 * oO[3][d0][mq]) * inv;
      float e1 = (a0 * oO[0][d1][mq] + a1 * oO[1][d1][mq] + a2 * oO[2][d1][mq] +
                  a3 * oO[3][d1][mq]) * inv;
      pw[i] = (uint32_t)f2bf(e0) | ((uint32_t)f2bf(e1) << 16);
    }
    pkv.x = pw[0]; pkv.y = pw[1]; pkv.z = pw[2]; pkv.w = pw[3];
    *(uint4*)(ao + (size_t)(qb + mq) * DMODEL + h64 + dbse) = pkv;
  }
}

// ---------------------------------------------------------------------------
extern "C" void kernel_launch(void* const* d_in, const int* in_sizes, int n_in,
                              void* d_out, int out_size, void* d_ws, size_t ws_size,
                              hipStream_t stream) {
  const float* x = (const float*)d_in[0];
  const int* offs = (const int*)d_in[1];
  const float* fcos = (const float*)d_in[2];
  const float* fsin = (const float*)d_in[3];
  const float* ln0g = (const float*)d_in[4];
  const float* ln0b = (const float*)d_in[5];
  const float* ln1g = (const float*)d_in[6];
  const float* ln1b = (const float*)d_in[7];
  const float* wqkv = (const float*)d_in[8];
  const float* bqkv = (const float*)d_in[9];
  const float* wo = (const float*)d_in[10];
  const float* bo = (const float*)d_in[11];
  const float* wu = (const float*)d_in[12];
  const float* bu = (const float*)d_in[13];
  const float* wd = (const float*)d_in[14];
  const float* bd = (const float*)d_in[15];
  const float* lnfg = (const float*)d_in[16];
  const float* lnfb = (const float*)d_in[17];

  char* ws = (char*)d_ws;
  size_t off = 0;
  auto alloc = [&](size_t bytes) -> void* {
    void* p = ws + off;
    off += (bytes + 255) & ~(size_t)255;
    return p;
  };
  bf16* wqkvT = (bf16*)alloc((size_t)NLAYER * 3 * DMODEL * DMODEL * 2);
  bf16* woT = (bf16*)alloc((size_t)NLAYER * DMODEL * DMODEL * 2);
  bf16* wuT = (bf16*)alloc((size_t)NLAYER * DMODEL * FFDIM * 2);
  bf16* wdT = (bf16*)alloc((size_t)NLAYER * FFDIM * DMODEL * 2);
  float* hbuf = (float*)alloc((size_t)S_LEN * DMODEL * 4);
  bf16* ybuf = (bf16*)alloc((size_t)S_LEN * DMODEL * 2);   // partDN head space
  bf16* qkv = (bf16*)alloc((size_t)S_LEN * 3 * DMODEL * 2);
  bf16* qrb = (bf16*)alloc((size_t)S_LEN * DMODEL * 2);
  bf16* krb = (bf16*)alloc((size_t)S_LEN * DMODEL * 2);
  bf16* vTb = (bf16*)alloc((size_t)S_LEN * DMODEL * 2);
  bf16* aob = (bf16*)alloc((size_t)S_LEN * DMODEL * 2);
  bf16* midb = (bf16*)alloc((size_t)S_LEN * FFDIM * 2);
  bf16* ybuf2 = (bf16*)alloc((size_t)S_LEN * DMODEL * 2);  // LN outputs (A operand)

  float* partWO = (float*)qkv;
  float* partDN = (float*)ybuf;

  for (int ly = 0; ly < NLAYER; ++ly) {
    k_tcast<<<dim3(3 * DMODEL / 32, DMODEL / 32), 256, 0, stream>>>(
        wqkv + (size_t)ly * DMODEL * 3 * DMODEL, wqkvT + (size_t)ly * 3 * DMODEL * DMODEL, DMODEL, 3 * DMODEL);
    k_tcast<<<dim3(DMODEL / 32, DMODEL / 32), 256, 0, stream>>>(
        wo + (size_t)ly * DMODEL * DMODEL, woT + (size_t)ly * DMODEL * DMODEL, DMODEL, DMODEL);
    k_tcast<<<dim3(FFDIM / 32, DMODEL / 32), 256, 0, stream>>>(
        wu + (size_t)ly * DMODEL * FFDIM, wuT + (size_t)ly * DMODEL * FFDIM, DMODEL, FFDIM);
    k_tcast<<<dim3(DMODEL / 32, FFDIM / 32), 256, 0, stream>>>(
        wd + (size_t)ly * FFDIM * DMODEL, wdT + (size_t)ly * FFDIM * DMODEL, FFDIM, DMODEL);
  }
  hipMemcpyAsync(hbuf, x, (size_t)S_LEN * DMODEL * 4, hipMemcpyDeviceToDevice, stream);

  k_ln<bf16><<<S_LEN, 256, 0, stream>>>(hbuf, ln0g, ln0b, ybuf2);

  for (int ly = 0; ly < NLAYER; ++ly) {
    // QKV: M=2048, N=3072, K=1024  (grid 16x24 = 384)
    k_gemm2<0, 128><<<dim3(S_LEN / 128, 3 * DMODEL / 128, 1), 256, 0, stream>>>(
        ybuf2, wqkvT + (size_t)ly * 3 * DMODEL * DMODEL, bqkv + ly * 3 * DMODEL, qkv,
        S_LEN, 3 * DMODEL, DMODEL, DMODEL);
    k_ropetv<<<dim3(S_LEN / 64, NHEAD), 256, 0, stream>>>(qkv, fcos, fsin, qrb, krb, vTb);
    k_attn<<<dim3(NHEAD, S_LEN / 32), 256, 0, stream>>>(qrb, krb, vTb, offs, aob);
    // WO: M=2048, N=1024, K=1024, split-K 2, BM=64  (xy grid 32x8 = 256)
    k_gemm2<3, 64><<<dim3(S_LEN / 64, DMODEL / 128, 2), 256, 0, stream>>>(
        aob, woT + (size_t)ly * DMODEL * DMODEL, nullptr, partWO,
        S_LEN, DMODEL, DMODEL, DMODEL / 2);
    k_redln<2, bf16><<<S_LEN, 256, 0, stream>>>(
        partWO, bo + ly * DMODEL, hbuf, ln1g + ly * DMODEL, ln1b + ly * DMODEL, ybuf2);
    // UP: M=2048, N=4096, K=1024  (grid 16x32 = 512)
    k_gemm2<2, 128><<<dim3(S_LEN / 128, FFDIM / 128, 1), 256, 0, stream>>>(
        ybuf2, wuT + (size_t)ly * DMODEL * FFDIM, bu + ly * FFDIM, midb,
        S_LEN, FFDIM, DMODEL, DMODEL);
    // DOWN: M=2048, N=1024, K=4096, split-K 4, BM=128  (xy grid 16x8 = 128)
    k_gemm2<3, 128><<<dim3(S_LEN / 128, DMODEL / 128, 4), 256, 0, stream>>>(
        midb, wdT + (size_t)ly * FFDIM * DMODEL, nullptr, partDN,
        S_LEN, DMODEL, FFDIM, FFDIM / 4);
    if (ly + 1 < NLAYER) {
      k_redln<4, bf16><<<S_LEN, 256, 0, stream>>>(
          partDN, bd + ly * DMODEL, hbuf, ln0g + (ly + 1) * DMODEL,
          ln0b + (ly + 1) * DMODEL, ybuf2);
    } else {
      k_redln<4, float><<<S_LEN, 256, 0, stream>>>(
          partDN, bd + ly * DMODEL, hbuf, lnfg, lnfb, (float*)d_out);
    }
  }
}

// Round 20
// 380.095 us; speedup vs baseline: 1.5343x; 1.0155x over previous
//
#include <hip/hip_runtime.h>
#include <hip/hip_bf16.h>
#include <stdint.h>
#include <math.h>

#define S_LEN 2048
#define DMODEL 1024
#define NHEAD 16
#define DHEAD 64
#define FFDIM 4096
#define NLAYER 2

using bf16 = __hip_bfloat16;
typedef __attribute__((ext_vector_type(8))) short bf16x8;
typedef __attribute__((ext_vector_type(4))) float f32x4;
typedef __attribute__((ext_vector_type(16))) float f32x16;
typedef __attribute__((ext_vector_type(4))) int i32x4;

#define MFMA16x16(A, B, C) __builtin_amdgcn_mfma_f32_16x16x32_bf16(A, B, C, 0, 0, 0)
#define MFMA32x32(A, B, C) __builtin_amdgcn_mfma_f32_32x32x16_bf16(A, B, C, 0, 0, 0)
#define EXP2(x) __builtin_amdgcn_exp2f(x)

__device__ __forceinline__ float bf2f(uint32_t u16bits) {
  union { uint32_t i; float f; } x;
  x.i = u16bits << 16;
  return x.f;
}
__device__ __forceinline__ uint16_t f2bf(float f) {
  return __builtin_bit_cast(uint16_t, __float2bfloat16(f));
}

// v_cvt_pk_bf16_f32: pack two f32 -> one dword of 2 bf16 (no builtin on gfx950)
__device__ __forceinline__ uint32_t cvtpk(float lo, float hi) {
  uint32_t r;
  asm("v_cvt_pk_bf16_f32 %0, %1, %2" : "=v"(r) : "v"(lo), "v"(hi));
  return r;
}
// v_permlane32_swap_b32
__device__ __forceinline__ void pl32swap(uint32_t& a, uint32_t& b) {
#if __has_builtin(__builtin_amdgcn_permlane32_swap)
  typedef __attribute__((ext_vector_type(2))) int i32x2;
  i32x2 r = __builtin_amdgcn_permlane32_swap((int)a, (int)b, false, false);
  a = (uint32_t)r.x;
  b = (uint32_t)r.y;
#else
  asm volatile("v_permlane32_swap_b32 %0, %1" : "+v"(a), "+v"(b));
#endif
}

// ---------------------------------------------------------------------------
// Weight cast + transpose: in fp32 (R x C)  ->  out bf16 (C x R)
// ---------------------------------------------------------------------------
__global__ __launch_bounds__(256) void k_tcast(const float* __restrict__ in,
                                               bf16* __restrict__ out,
                                               int R, int C) {
  __shared__ float tl[32][33];
  int t = threadIdx.x;
  int r0 = blockIdx.y * 32, c0 = blockIdx.x * 32;
  int cl = t & 31, rl = t >> 5;
#pragma unroll
  for (int i = 0; i < 4; ++i)
    tl[rl + i * 8][cl] = in[(size_t)(r0 + rl + i * 8) * C + c0 + cl];
  __syncthreads();
#pragma unroll
  for (int i = 0; i < 4; ++i)
    out[(size_t)(c0 + rl + i * 8) * R + r0 + cl] = __float2bfloat16(tl[cl][rl + i * 8]);
}

// ---------------------------------------------------------------------------
// LayerNorm helpers
// ---------------------------------------------------------------------------
__device__ __forceinline__ void ln_store4(bf16* p, float a, float b, float c, float d) {
  uint2 u;
  u.x = (uint32_t)f2bf(a) | ((uint32_t)f2bf(b) << 16);
  u.y = (uint32_t)f2bf(c) | ((uint32_t)f2bf(d) << 16);
  *(uint2*)p = u;
}
__device__ __forceinline__ void ln_store4(float* p, float a, float b, float c, float d) {
  *(float4*)p = make_float4(a, b, c, d);
}

// row-wide (1024) LN from 4 per-thread values; block = 256 threads
template <typename OUT>
__device__ __forceinline__ void ln_rowcore(float v0, float v1, float v2, float v3,
                                           const float* __restrict__ g,
                                           const float* __restrict__ b,
                                           OUT* __restrict__ yrow, int t) {
  float s = v0 + v1 + v2 + v3;
  float s2 = v0 * v0 + v1 * v1 + v2 * v2 + v3 * v3;
#pragma unroll
  for (int off = 32; off > 0; off >>= 1) {
    s += __shfl_down(s, off);
    s2 += __shfl_down(s2, off);
  }
  __shared__ float red[8];
  int w = t >> 6;
  if ((t & 63) == 0) { red[w] = s; red[4 + w] = s2; }
  __syncthreads();
  s = red[0] + red[1] + red[2] + red[3];
  s2 = red[4] + red[5] + red[6] + red[7];
  float mean = s * (1.0f / DMODEL);
  float var = s2 * (1.0f / DMODEL) - mean * mean;
  float rstd = rsqrtf(var + 1e-5f);
  float4 gv = ((const float4*)g)[t];
  float4 bv = ((const float4*)b)[t];
  ln_store4(yrow + t * 4, (v0 - mean) * rstd * gv.x + bv.x,
            (v1 - mean) * rstd * gv.y + bv.y, (v2 - mean) * rstd * gv.z + bv.z,
            (v3 - mean) * rstd * gv.w + bv.w);
}

template <typename OUT>
__global__ __launch_bounds__(256) void k_ln(const float* __restrict__ h,
                                            const float* __restrict__ g,
                                            const float* __restrict__ b,
                                            OUT* __restrict__ y) {
  int row = blockIdx.x, t = threadIdx.x;
  const float4 v = ((const float4*)(h + (size_t)row * DMODEL))[t];
  ln_rowcore<OUT>(v.x, v.y, v.z, v.w, g, b, y + (size_t)row * DMODEL, t);
}

// ---------------------------------------------------------------------------
// Fused split-K merge + residual + LayerNorm:
//   hnew = hin + bias + sum_ks part[ks];  if (WB) hb := hnew;  y := LN(hnew)
// hin decouples the residual source (x on layer 0 -> no memcpy); WB=false
// skips the dead hbuf writeback on the final layer.
// ---------------------------------------------------------------------------
template <int KS, typename OUT, bool WB>
__global__ __launch_bounds__(256) void k_redln(const float* __restrict__ part,
                                               const float* __restrict__ bias,
                                               const float* __restrict__ hin,
                                               float* __restrict__ hb,
                                               const float* __restrict__ g,
                                               const float* __restrict__ b,
                                               OUT* __restrict__ y) {
  int row = blockIdx.x, t = threadIdx.x;
  size_t base = (size_t)row * DMODEL + t * 4;
  float4 r = *(const float4*)(hin + base);
  float4 bv = *(const float4*)(bias + t * 4);
  float v0 = r.x + bv.x, v1 = r.y + bv.y, v2 = r.z + bv.z, v3 = r.w + bv.w;
#pragma unroll
  for (int ks = 0; ks < KS; ++ks) {
    float4 p = *(const float4*)(part + (size_t)ks * (S_LEN * DMODEL) + base);
    v0 += p.x; v1 += p.y; v2 += p.z; v3 += p.w;
  }
  if (WB) *(float4*)(hb + base) = make_float4(v0, v1, v2, v3);
  ln_rowcore<OUT>(v0, v1, v2, v3, g, b, y + (size_t)row * DMODEL, t);
}

// ---------------------------------------------------------------------------
// Fused RoPE (q,k) + V transpose. Grid (S/64, NHEAD), 256 threads.
// ---------------------------------------------------------------------------
__global__ __launch_bounds__(256) void k_ropetv(const bf16* __restrict__ qkv,
                                                const float* __restrict__ fcos,
                                                const float* __restrict__ fsin,
                                                bf16* __restrict__ qr,
                                                bf16* __restrict__ kr,
                                                bf16* __restrict__ vT) {
  __shared__ bf16 tl[64][65];
  int t = threadIdx.x;
  int hh = blockIdx.y;
  int sb = blockIdx.x * 64;
#pragma unroll
  for (int i = 0; i < 8; ++i) {
    int e = i * 256 + t;
    int p = e & 31, sl = e >> 5;
    int s = sb + sl;
    float c = fcos[s * 32 + p], sn = fsin[s * 32 + p];
    int colq = hh * DHEAD + 2 * p;
    uint32_t rq = *(const uint32_t*)(qkv + (size_t)s * 3 * DMODEL + colq);
    uint32_t rk = *(const uint32_t*)(qkv + (size_t)s * 3 * DMODEL + DMODEL + colq);
    {
      float te = bf2f(rq & 0xffffu), to = bf2f(rq >> 16);
      uint32_t outv = (uint32_t)f2bf(te * c - to * sn) | ((uint32_t)f2bf(te * sn + to * c) << 16);
      *(uint32_t*)(qr + (size_t)s * DMODEL + colq) = outv;
    }
    {
      float te = bf2f(rk & 0xffffu), to = bf2f(rk >> 16);
      uint32_t outv = (uint32_t)f2bf(te * c - to * sn) | ((uint32_t)f2bf(te * sn + to * c) << 16);
      *(uint32_t*)(kr + (size_t)s * DMODEL + colq) = outv;
    }
  }
#pragma unroll
  for (int i = 0; i < 16; ++i) {
    int e = i * 256 + t;
    int sl = e >> 6, d = e & 63;
    tl[sl][d] = qkv[(size_t)(sb + sl) * 3 * DMODEL + 2 * DMODEL + hh * DHEAD + d];
  }
  __syncthreads();
#pragma unroll
  for (int i = 0; i < 16; ++i) {
    int e = i * 256 + t;
    int d = e >> 6, sl = e & 63;
    vT[(size_t)(hh * DHEAD + d) * S_LEN + sb + sl] = tl[sl][d];
  }
}

// ---------------------------------------------------------------------------
// GEMM (session-best config): BM x 128 tile, BK=64, T2 XOR swizzle, T1 XCD
// swizzle, split-K via z, counted-vmcnt 2-deep prefetch, raw s_barrier.
// EPI 0: bias -> bf16.  EPI 2: gelu(bias) -> bf16.  EPI 3: raw fp32 partial.
// ---------------------------------------------------------------------------
template <int EPI, int BM>
__global__ __launch_bounds__(256) void k_gemm2(const bf16* __restrict__ A,
                                               const bf16* __restrict__ BT,
                                               const float* __restrict__ bias,
                                               void* __restrict__ out,
                                               int M, int N, int K, int Kc) {
  constexpr int MF = BM / 32;  // m-frags per wave
  __shared__ bf16 As[2][BM * 64];
  __shared__ bf16 Bs[2][128 * 64];
  int t = threadIdx.x;
  int w = t >> 6, l = t & 63, lr = l & 15, lg = l >> 4;

  int nxy = gridDim.x * gridDim.y;
  int bid = blockIdx.y * gridDim.x + blockIdx.x;
  int chk8 = nxy >> 3;
  int swz = (bid & 7) * chk8 + (bid >> 3);
  int bx = swz % gridDim.x, by = swz / gridDim.x;
  int bm = bx * BM, bn = by * 128;
  int k0 = blockIdx.z * Kc;
  int wm = (w >> 1) * (BM / 2), wn = (w & 1) * 64;

  f32x4 zero4 = {0.f, 0.f, 0.f, 0.f};
  f32x4 acc[MF][4];
#pragma unroll
  for (int mf = 0; mf < MF; ++mf)
#pragma unroll
    for (int nf = 0; nf < 4; ++nf) acc[mf][nf] = zero4;

  auto stage = [&](int buf, int kk) {
#pragma unroll
    for (int i = 0; i < BM / 32; ++i) {
      int chunk = i * 256 + t;
      int row = chunk >> 3;
      int scol = ((chunk ^ row) & 7) << 3;
      __builtin_amdgcn_global_load_lds(
          (__attribute__((address_space(1))) void*)(A + (size_t)(bm + row) * K + kk + scol),
          (__attribute__((address_space(3))) void*)(&As[buf][chunk * 8]), 16, 0, 0);
    }
#pragma unroll
    for (int i = 0; i < 4; ++i) {
      int chunk = i * 256 + t;
      int row = chunk >> 3;
      int scol = ((chunk ^ row) & 7) << 3;
      __builtin_amdgcn_global_load_lds(
          (__attribute__((address_space(1))) void*)(BT + (size_t)(bn + row) * K + kk + scol),
          (__attribute__((address_space(3))) void*)(&Bs[buf][chunk * 8]), 16, 0, 0);
    }
  };

  int nt = Kc / 64;
  stage(0, k0);
  stage(1, k0 + 64);  // 2 tiles in flight (nt >= 8 for all our shapes)
  int cur = 0;
  for (int kt = 0; kt < nt; ++kt) {
    // wait for the OLDEST stage (tile kt) only; tile kt+1 stays in flight
    if (kt + 1 < nt) {
      if constexpr (BM == 128)
        asm volatile("s_waitcnt vmcnt(8)" ::: "memory");
      else
        asm volatile("s_waitcnt vmcnt(6)" ::: "memory");
    } else {
      asm volatile("s_waitcnt vmcnt(0)" ::: "memory");
    }
    __builtin_amdgcn_s_barrier();  // all waves' tile-kt loads landed
    __builtin_amdgcn_sched_barrier(0);
    bf16x8 af[2][MF], bfr[2][4];
#pragma unroll
    for (int h = 0; h < 2; ++h) {
#pragma unroll
      for (int mf = 0; mf < MF; ++mf) {
        int row = wm + mf * 16 + lr;
        af[h][mf] = *(const bf16x8*)(&As[cur][row * 64 + ((((h << 2) + lg) ^ (row & 7)) << 3)]);
      }
#pragma unroll
      for (int nf = 0; nf < 4; ++nf) {
        int row = wn + nf * 16 + lr;
        bfr[h][nf] = *(const bf16x8*)(&Bs[cur][row * 64 + ((((h << 2) + lg) ^ (row & 7)) << 3)]);
      }
    }
    asm volatile("s_waitcnt lgkmcnt(0)" ::: "memory");
    __builtin_amdgcn_sched_barrier(0);
    __builtin_amdgcn_s_barrier();  // all waves done reading buf[cur]
    if (kt + 2 < nt) stage(cur, k0 + (kt + 2) * 64);  // refill freed buffer
    __builtin_amdgcn_sched_barrier(0);
#pragma unroll
    for (int h = 0; h < 2; ++h)
#pragma unroll
      for (int mf = 0; mf < MF; ++mf)
#pragma unroll
        for (int nf = 0; nf < 4; ++nf)
          acc[mf][nf] = MFMA16x16(af[h][mf], bfr[h][nf], acc[mf][nf]);
    cur ^= 1;
  }

  if (EPI == 3) {
    float* outf = (float*)out + (size_t)blockIdx.z * ((size_t)M * N);
#pragma unroll
    for (int mf = 0; mf < MF; ++mf)
#pragma unroll
      for (int nf = 0; nf < 4; ++nf) {
        int col = bn + wn + nf * 16 + lr;
        int row0 = bm + wm + mf * 16 + lg * 4;
#pragma unroll
        for (int r = 0; r < 4; ++r)
          outf[(size_t)(row0 + r) * N + col] = acc[mf][nf][r];
      }
  } else {
    bf16* outb = (bf16*)out;
#pragma unroll
    for (int mf = 0; mf < MF; ++mf)
#pragma unroll
      for (int nf = 0; nf < 4; ++nf) {
        int col = bn + wn + nf * 16 + lr;
        float bv = bias[col];
        int row0 = bm + wm + mf * 16 + lg * 4;
#pragma unroll
        for (int r = 0; r < 4; ++r) {
          float v = acc[mf][nf][r] + bv;
          if (EPI == 2)
            v = 0.5f * v * (1.0f + tanhf(0.7978845608028654f * (v + 0.044715f * v * v * v)));
          outb[(size_t)(row0 + r) * N + col] = __float2bfloat16(v);
        }
      }
  }
}

// ---------------------------------------------------------------------------
// Flash attention v7 (stable body: 4-wave split-K, swapped-operand 32x32x16,
// in-register softmax via cvt_pk+permlane, defer-max, 2-deep K register
// pipeline with named registers). VGPR-cliff: no added control flow.
// ---------------------------------------------------------------------------
#define ATTN_TILE(KC0, KC1, KC2, KC3, KN0, KN1, KN2, KN3, IT)                  \
  {                                                                            \
    const int j0 = jbase + (IT) * 32;                                          \
    f32x16 sC;                                                                 \
    _Pragma("unroll") for (int r = 0; r < 16; ++r) sC[r] = 0.f;                \
    __builtin_amdgcn_s_setprio(1);                                             \
    sC = MFMA32x32(KC0, qf0, sC);                                              \
    sC = MFMA32x32(KC1, qf1, sC);                                              \
    sC = MFMA32x32(KC2, qf2, sC);                                              \
    sC = MFMA32x32(KC3, qf3, sC);                                              \
    __builtin_amdgcn_s_setprio(0);                                             \
    const bf16* vbase = vrow + j0;                                             \
    bf16x8 va00 = *(const bf16x8*)(vbase);                                     \
    bf16x8 va01 = *(const bf16x8*)(vbase + 16);                                \
    bf16x8 va10 = *(const bf16x8*)(vbase + 32 * S_LEN);                        \
    bf16x8 va11 = *(const bf16x8*)(vbase + 32 * S_LEN + 16);                   \
    {                                                                          \
      int jn = j0 + 32;                                                        \
      int jmax = jbase + 480;                                                  \
      jn = (jn > jmax) ? jmax : jn;                                            \
      const bf16* kn = krow + (size_t)jn * DMODEL;                             \
      KN0 = *(const bf16x8*)(kn);                                              \
      KN1 = *(const bf16x8*)(kn + 16);                                         \
      KN2 = *(const bf16x8*)(kn + 32);                                         \
      KN3 = *(const bf16x8*)(kn + 48);                                         \
    }                                                                          \
    int tt = j0 + hi * 4 - sl0;                                                \
    _Pragma("unroll") for (int r = 0; r < 16; ++r) {                           \
      int ku = tt + ((r & 3) + 8 * (r >> 2));                                  \
      float fb = ((uint32_t)ku < spanu) ? LOG2E : 0.0f;                        \
      sC[r] = sC[r] * C1 + fb;                                                 \
    }                                                                          \
    float rm = sC[0];                                                          \
    _Pragma("unroll") for (int r = 1; r < 16; ++r) rm = fmaxf(rm, sC[r]);      \
    uint32_t ra = __builtin_bit_cast(uint32_t, rm), rb = ra;                   \
    pl32swap(ra, rb);                                                          \
    float rmax =                                                               \
        fmaxf(__builtin_bit_cast(float, ra), __builtin_bit_cast(float, rb));   \
    if (__any(rmax > m_r + 8.0f)) {                                            \
      float mn = fmaxf(m_r, rmax);                                             \
      float fs = EXP2(m_r - mn);                                               \
      m_r = mn;                                                                \
      l_r *= fs;                                                               \
      _Pragma("unroll") for (int r = 0; r < 16; ++r) {                         \
        oC0[r] *= fs;                                                          \
        oC1[r] *= fs;                                                          \
      }                                                                        \
    }                                                                          \
    _Pragma("unroll") for (int r = 0; r < 16; ++r) {                           \
      float pv = EXP2(sC[r] - m_r);                                            \
      sC[r] = pv;                                                              \
      l_r += pv;                                                               \
    }                                                                          \
    uint32_t u0 = cvtpk(sC[0], sC[1]), u1 = cvtpk(sC[2], sC[3]);               \
    uint32_t u2 = cvtpk(sC[4], sC[5]), u3 = cvtpk(sC[6], sC[7]);               \
    uint32_t u4 = cvtpk(sC[8], sC[9]), u5 = cvtpk(sC[10], sC[11]);             \
    uint32_t u6 = cvtpk(sC[12], sC[13]), u7 = cvtpk(sC[14], sC[15]);           \
    pl32swap(u0, u2);                                                          \
    pl32swap(u1, u3);                                                          \
    pl32swap(u4, u6);                                                          \
    pl32swap(u5, u7);                                                          \
    i32x4 pi0 = {(int)u0, (int)u1, (int)u2, (int)u3};                          \
    i32x4 pi1 = {(int)u4, (int)u5, (int)u6, (int)u7};                          \
    bf16x8 pb0 = __builtin_bit_cast(bf16x8, pi0);                              \
    bf16x8 pb1 = __builtin_bit_cast(bf16x8, pi1);                              \
    __builtin_amdgcn_s_setprio(1);                                             \
    oC0 = MFMA32x32(va00, pb0, oC0);                                           \
    oC0 = MFMA32x32(va01, pb1, oC0);                                           \
    oC1 = MFMA32x32(va10, pb0, oC1);                                           \
    oC1 = MFMA32x32(va11, pb1, oC1);                                           \
    __builtin_amdgcn_s_setprio(0);                                             \
  }

__global__ __launch_bounds__(256, 4) void k_attn(const bf16* __restrict__ qr,
                                                 const bf16* __restrict__ kr,
                                                 const bf16* __restrict__ vT,
                                                 const int* __restrict__ offs,
                                                 bf16* __restrict__ ao) {
  __shared__ float oO[4][64][33];
  __shared__ float mM[4][32];
  __shared__ float lL[4][32];

  int t = threadIdx.x, w = t >> 6, l = t & 63;
  int ql = l & 31, hi = l >> 5, hi8 = hi * 8;
  int hh = blockIdx.x, qb = blockIdx.y * 32;
  int h64 = hh * DHEAD;

  constexpr float LOG2E = 1.4426950408889634f;
  constexpr float C1 = 0.125f * LOG2E;

  int q = qb + ql;
  int o0 = offs[0], o1 = offs[1], o2 = offs[2], o3 = offs[3], o4 = offs[4];
  int sl0 = -1073741824, sh0 = 1073741824;
  sl0 = (o0 <= q) ? o0 : sl0;
  sl0 = (o1 <= q) ? o1 : sl0;
  sl0 = (o2 <= q) ? o2 : sl0;
  sl0 = (o3 <= q) ? o3 : sl0;
  sl0 = (o4 <= q) ? o4 : sl0;
  sh0 = (o4 > q) ? o4 : sh0;
  sh0 = (o3 > q) ? o3 : sh0;
  sh0 = (o2 > q) ? o2 : sh0;
  sh0 = (o1 > q) ? o1 : sh0;
  sh0 = (o0 > q) ? o0 : sh0;
  uint32_t spanu = (uint32_t)(sh0 - sl0);

  const bf16* qbase = qr + (size_t)q * DMODEL + h64 + hi8;
  bf16x8 qf0 = *(const bf16x8*)(qbase);
  bf16x8 qf1 = *(const bf16x8*)(qbase + 16);
  bf16x8 qf2 = *(const bf16x8*)(qbase + 32);
  bf16x8 qf3 = *(const bf16x8*)(qbase + 48);

  f32x16 oC0, oC1;
#pragma unroll
  for (int r = 0; r < 16; ++r) { oC0[r] = 0.f; oC1[r] = 0.f; }
  float m_r = -1e30f, l_r = 0.f;

  const bf16* vrow = vT + (size_t)(h64 + ql) * S_LEN + hi8;
  const bf16* krow = kr + (size_t)ql * DMODEL + h64 + hi8;
  int jbase = w * 512;

  bf16x8 kA0, kA1, kA2, kA3, kB0, kB1, kB2, kB3;
  {
    const bf16* kb = krow + (size_t)jbase * DMODEL;
    kA0 = *(const bf16x8*)(kb);
    kA1 = *(const bf16x8*)(kb + 16);
    kA2 = *(const bf16x8*)(kb + 32);
    kA3 = *(const bf16x8*)(kb + 48);
  }

  for (int itp = 0; itp < 8; ++itp) {
    ATTN_TILE(kA0, kA1, kA2, kA3, kB0, kB1, kB2, kB3, itp * 2);
    ATTN_TILE(kB0, kB1, kB2, kB3, kA0, kA1, kA2, kA3, itp * 2 + 1);
  }

  {
    uint32_t la = __builtin_bit_cast(uint32_t, l_r), lb = la;
    pl32swap(la, lb);
    l_r = __builtin_bit_cast(float, la) + __builtin_bit_cast(float, lb);
  }
  if (hi == 0) {
    mM[w][ql] = m_r;
    lL[w][ql] = l_r;
  }
#pragma unroll
  for (int r = 0; r < 16; ++r) {
    int d = (r & 3) + 8 * (r >> 2) + 4 * hi;
    oO[w][d][ql] = oC0[r];
    oO[w][d + 32][ql] = oC1[r];
  }
  __syncthreads();

  {
    int mq = t & 31, dbse = (t >> 5) * 8;
    float m0 = mM[0][mq], m1 = mM[1][mq], m2 = mM[2][mq], m3 = mM[3][mq];
    float ms = fmaxf(fmaxf(m0, m1), fmaxf(m2, m3));
    float a0 = EXP2(m0 - ms), a1 = EXP2(m1 - ms), a2 = EXP2(m2 - ms), a3 = EXP2(m3 - ms);
    float ll = a0 * lL[0][mq] + a1 * lL[1][mq] + a2 * lL[2][mq] + a3 * lL[3][mq];
    float inv = 1.0f / ll;
    uint4 pkv;
    uint32_t pw[4];
#pragma unroll
    for (int i = 0; i < 4; ++i) {
      int d0 = dbse + 2 * i, d1 = dbse + 2 * i + 1;
      float e0 = (a0 * oO[0][d0][mq] + a1 * oO[1][d0][mq] + a2 * oO[2][d0][mq] +
                  a3 * oO[3][d0][mq]) * inv;
      float e1 = (a0 * oO[0][d1][mq] + a1 * oO[1][d1][mq] + a2 * oO[2][d1][mq] +
                  a3 * oO[3][d1][mq]) * inv;
      pw[i] = (uint32_t)f2bf(e0) | ((uint32_t)f2bf(e1) << 16);
    }
    pkv.x = pw[0]; pkv.y = pw[1]; pkv.z = pw[2]; pkv.w = pw[3];
    *(uint4*)(ao + (size_t)(qb + mq) * DMODEL + h64 + dbse) = pkv;
  }
}

// ---------------------------------------------------------------------------
extern "C" void kernel_launch(void* const* d_in, const int* in_sizes, int n_in,
                              void* d_out, int out_size, void* d_ws, size_t ws_size,
                              hipStream_t stream) {
  const float* x = (const float*)d_in[0];
  const int* offs = (const int*)d_in[1];
  const float* fcos = (const float*)d_in[2];
  const float* fsin = (const float*)d_in[3];
  const float* ln0g = (const float*)d_in[4];
  const float* ln0b = (const float*)d_in[5];
  const float* ln1g = (const float*)d_in[6];
  const float* ln1b = (const float*)d_in[7];
  const float* wqkv = (const float*)d_in[8];
  const float* bqkv = (const float*)d_in[9];
  const float* wo = (const float*)d_in[10];
  const float* bo = (const float*)d_in[11];
  const float* wu = (const float*)d_in[12];
  const float* bu = (const float*)d_in[13];
  const float* wd = (const float*)d_in[14];
  const float* bd = (const float*)d_in[15];
  const float* lnfg = (const float*)d_in[16];
  const float* lnfb = (const float*)d_in[17];

  char* ws = (char*)d_ws;
  size_t off = 0;
  auto alloc = [&](size_t bytes) -> void* {
    void* p = ws + off;
    off += (bytes + 255) & ~(size_t)255;
    return p;
  };
  bf16* wqkvT = (bf16*)alloc((size_t)NLAYER * 3 * DMODEL * DMODEL * 2);
  bf16* woT = (bf16*)alloc((size_t)NLAYER * DMODEL * DMODEL * 2);
  bf16* wuT = (bf16*)alloc((size_t)NLAYER * DMODEL * FFDIM * 2);
  bf16* wdT = (bf16*)alloc((size_t)NLAYER * FFDIM * DMODEL * 2);
  float* hbuf = (float*)alloc((size_t)S_LEN * DMODEL * 4);
  bf16* ybuf = (bf16*)alloc((size_t)S_LEN * DMODEL * 2);   // partDN head space
  bf16* qkv = (bf16*)alloc((size_t)S_LEN * 3 * DMODEL * 2);
  bf16* qrb = (bf16*)alloc((size_t)S_LEN * DMODEL * 2);
  bf16* krb = (bf16*)alloc((size_t)S_LEN * DMODEL * 2);
  bf16* vTb = (bf16*)alloc((size_t)S_LEN * DMODEL * 2);
  bf16* aob = (bf16*)alloc((size_t)S_LEN * DMODEL * 2);
  bf16* midb = (bf16*)alloc((size_t)S_LEN * FFDIM * 2);
  bf16* ybuf2 = (bf16*)alloc((size_t)S_LEN * DMODEL * 2);  // LN outputs (A operand)

  float* partWO = (float*)qkv;
  float* partDN = (float*)ybuf;

  for (int ly = 0; ly < NLAYER; ++ly) {
    k_tcast<<<dim3(3 * DMODEL / 32, DMODEL / 32), 256, 0, stream>>>(
        wqkv + (size_t)ly * DMODEL * 3 * DMODEL, wqkvT + (size_t)ly * 3 * DMODEL * DMODEL, DMODEL, 3 * DMODEL);
    k_tcast<<<dim3(DMODEL / 32, DMODEL / 32), 256, 0, stream>>>(
        wo + (size_t)ly * DMODEL * DMODEL, woT + (size_t)ly * DMODEL * DMODEL, DMODEL, DMODEL);
    k_tcast<<<dim3(FFDIM / 32, DMODEL / 32), 256, 0, stream>>>(
        wu + (size_t)ly * DMODEL * FFDIM, wuT + (size_t)ly * DMODEL * FFDIM, DMODEL, FFDIM);
    k_tcast<<<dim3(DMODEL / 32, FFDIM / 32), 256, 0, stream>>>(
        wd + (size_t)ly * FFDIM * DMODEL, wdT + (size_t)ly * FFDIM * DMODEL, FFDIM, DMODEL);
  }

  // layer-0 entry LN reads x directly (no x->hbuf memcpy; layer-0 WO-redln
  // uses x as the residual source and performs the first hbuf write)
  k_ln<bf16><<<S_LEN, 256, 0, stream>>>(x, ln0g, ln0b, ybuf2);

  for (int ly = 0; ly < NLAYER; ++ly) {
    // QKV: M=2048, N=3072, K=1024  (grid 16x24 = 384)
    k_gemm2<0, 128><<<dim3(S_LEN / 128, 3 * DMODEL / 128, 1), 256, 0, stream>>>(
        ybuf2, wqkvT + (size_t)ly * 3 * DMODEL * DMODEL, bqkv + ly * 3 * DMODEL, qkv,
        S_LEN, 3 * DMODEL, DMODEL, DMODEL);
    k_ropetv<<<dim3(S_LEN / 64, NHEAD), 256, 0, stream>>>(qkv, fcos, fsin, qrb, krb, vTb);
    k_attn<<<dim3(NHEAD, S_LEN / 32), 256, 0, stream>>>(qrb, krb, vTb, offs, aob);
    // WO: M=2048, N=1024, K=1024, split-K 2, BM=64  (xy grid 32x8 = 256)
    k_gemm2<3, 64><<<dim3(S_LEN / 64, DMODEL / 128, 2), 256, 0, stream>>>(
        aob, woT + (size_t)ly * DMODEL * DMODEL, nullptr, partWO,
        S_LEN, DMODEL, DMODEL, DMODEL / 2);
    // fused: hbuf = (ly? hbuf : x) + bo + sum(partWO); ybuf2 = LN1(hbuf)
    k_redln<2, bf16, true><<<S_LEN, 256, 0, stream>>>(
        partWO, bo + ly * DMODEL, ly == 0 ? x : hbuf, hbuf,
        ln1g + ly * DMODEL, ln1b + ly * DMODEL, ybuf2);
    // UP: M=2048, N=4096, K=1024  (grid 16x32 = 512)
    k_gemm2<2, 128><<<dim3(S_LEN / 128, FFDIM / 128, 1), 256, 0, stream>>>(
        ybuf2, wuT + (size_t)ly * DMODEL * FFDIM, bu + ly * FFDIM, midb,
        S_LEN, FFDIM, DMODEL, DMODEL);
    // DOWN: M=2048, N=1024, K=4096, split-K 4, BM=128  (xy grid 16x8 = 128)
    k_gemm2<3, 128><<<dim3(S_LEN / 128, DMODEL / 128, 4), 256, 0, stream>>>(
        midb, wdT + (size_t)ly * FFDIM * DMODEL, nullptr, partDN,
        S_LEN, DMODEL, FFDIM, FFDIM / 4);
    if (ly + 1 < NLAYER) {
      k_redln<4, bf16, true><<<S_LEN, 256, 0, stream>>>(
          partDN, bd + ly * DMODEL, hbuf, hbuf, ln0g + (ly + 1) * DMODEL,
          ln0b + (ly + 1) * DMODEL, ybuf2);
    } else {
      // final: no hbuf writeback (dead), LNf straight to d_out
      k_redln<4, float, false><<<S_LEN, 256, 0, stream>>>(
          partDN, bd + ly * DMODEL, hbuf, hbuf, lnfg, lnfb, (float*)d_out);
    }
  }
}

// Round 21
// 367.527 us; speedup vs baseline: 1.5868x; 1.0342x over previous
//
#include <hip/hip_runtime.h>
#include <hip/hip_bf16.h>
#include <stdint.h>
#include <math.h>

#define S_LEN 2048
#define DMODEL 1024
#define NHEAD 16
#define DHEAD 64
#define FFDIM 4096
#define NLAYER 2

using bf16 = __hip_bfloat16;
typedef __attribute__((ext_vector_type(8))) short bf16x8;
typedef __attribute__((ext_vector_type(4))) float f32x4;
typedef __attribute__((ext_vector_type(16))) float f32x16;
typedef __attribute__((ext_vector_type(4))) int i32x4;

#define MFMA16x16(A, B, C) __builtin_amdgcn_mfma_f32_16x16x32_bf16(A, B, C, 0, 0, 0)
#define MFMA32x32(A, B, C) __builtin_amdgcn_mfma_f32_32x32x16_bf16(A, B, C, 0, 0, 0)
#define EXP2(x) __builtin_amdgcn_exp2f(x)

__device__ __forceinline__ float bf2f(uint32_t u16bits) {
  union { uint32_t i; float f; } x;
  x.i = u16bits << 16;
  return x.f;
}
__device__ __forceinline__ uint16_t f2bf(float f) {
  return __builtin_bit_cast(uint16_t, __float2bfloat16(f));
}

// v_cvt_pk_bf16_f32: pack two f32 -> one dword of 2 bf16 (no builtin on gfx950)
__device__ __forceinline__ uint32_t cvtpk(float lo, float hi) {
  uint32_t r;
  asm("v_cvt_pk_bf16_f32 %0, %1, %2" : "=v"(r) : "v"(lo), "v"(hi));
  return r;
}
// v_permlane32_swap_b32
__device__ __forceinline__ void pl32swap(uint32_t& a, uint32_t& b) {
#if __has_builtin(__builtin_amdgcn_permlane32_swap)
  typedef __attribute__((ext_vector_type(2))) int i32x2;
  i32x2 r = __builtin_amdgcn_permlane32_swap((int)a, (int)b, false, false);
  a = (uint32_t)r.x;
  b = (uint32_t)r.y;
#else
  asm volatile("v_permlane32_swap_b32 %0, %1" : "+v"(a), "+v"(b));
#endif
}

// ---------------------------------------------------------------------------
// Fused weight cast+transpose, ALL 8 weight matrices in ONE dispatch.
// Tile = 32 rows x 128 cols of fp32 source; float4 loads (16B/lane),
// ushort4 stores (8B/lane). Per-layer tiles: wqkv 768, wo 256, wu 1024,
// wd 1024 (sum 3072); x2 layers = 6144 blocks.
// ---------------------------------------------------------------------------
__global__ __launch_bounds__(256) void k_tcast_all(
    const float* __restrict__ wqkv, const float* __restrict__ wo,
    const float* __restrict__ wu, const float* __restrict__ wd,
    bf16* __restrict__ wqkvT, bf16* __restrict__ woT,
    bf16* __restrict__ wuT, bf16* __restrict__ wdT) {
  int bid = blockIdx.x;
  int ly = (bid >= 3072);
  int lid = bid - ly * 3072;
  const float* src;
  bf16* dst;
  int R, C;
  if (lid < 768) {
    src = wqkv; dst = wqkvT; R = 1024; C = 3072;
  } else if (lid < 1024) {
    lid -= 768; src = wo; dst = woT; R = 1024; C = 1024;
  } else if (lid < 2048) {
    lid -= 1024; src = wu; dst = wuT; R = 1024; C = 4096;
  } else {
    lid -= 2048; src = wd; dst = wdT; R = 4096; C = 1024;
  }
  src += (size_t)ly * R * C;
  dst += (size_t)ly * R * C;
  int tilesC = C >> 7;  // C/128
  int tr = lid / tilesC, tc = lid - tr * tilesC;
  int r0 = tr * 32, c0 = tc * 128;

  __shared__ float tl[32][132];
  int t = threadIdx.x;
  int lrow = t >> 5, lcv = (t & 31) * 4;
#pragma unroll
  for (int i = 0; i < 4; ++i) {
    int r = lrow + i * 8;
    float4 v = *(const float4*)(src + (size_t)(r0 + r) * C + c0 + lcv);
    tl[r][lcv] = v.x;
    tl[r][lcv + 1] = v.y;
    tl[r][lcv + 2] = v.z;
    tl[r][lcv + 3] = v.w;
  }
  __syncthreads();
#pragma unroll
  for (int i = 0; i < 4; ++i) {
    int idx = i * 256 + t;
    int c = idx >> 3, rq = (idx & 7) * 4;
    ushort4 o;
    o.x = f2bf(tl[rq][c]);
    o.y = f2bf(tl[rq + 1][c]);
    o.z = f2bf(tl[rq + 2][c]);
    o.w = f2bf(tl[rq + 3][c]);
    *(ushort4*)(dst + (size_t)(c0 + c) * R + r0 + rq) = o;
  }
}

// ---------------------------------------------------------------------------
// LayerNorm helpers
// ---------------------------------------------------------------------------
__device__ __forceinline__ void ln_store4(bf16* p, float a, float b, float c, float d) {
  uint2 u;
  u.x = (uint32_t)f2bf(a) | ((uint32_t)f2bf(b) << 16);
  u.y = (uint32_t)f2bf(c) | ((uint32_t)f2bf(d) << 16);
  *(uint2*)p = u;
}
__device__ __forceinline__ void ln_store4(float* p, float a, float b, float c, float d) {
  *(float4*)p = make_float4(a, b, c, d);
}

// row-wide (1024) LN from 4 per-thread values; block = 256 threads
template <typename OUT>
__device__ __forceinline__ void ln_rowcore(float v0, float v1, float v2, float v3,
                                           const float* __restrict__ g,
                                           const float* __restrict__ b,
                                           OUT* __restrict__ yrow, int t) {
  float s = v0 + v1 + v2 + v3;
  float s2 = v0 * v0 + v1 * v1 + v2 * v2 + v3 * v3;
#pragma unroll
  for (int off = 32; off > 0; off >>= 1) {
    s += __shfl_down(s, off);
    s2 += __shfl_down(s2, off);
  }
  __shared__ float red[8];
  int w = t >> 6;
  if ((t & 63) == 0) { red[w] = s; red[4 + w] = s2; }
  __syncthreads();
  s = red[0] + red[1] + red[2] + red[3];
  s2 = red[4] + red[5] + red[6] + red[7];
  float mean = s * (1.0f / DMODEL);
  float var = s2 * (1.0f / DMODEL) - mean * mean;
  float rstd = rsqrtf(var + 1e-5f);
  float4 gv = ((const float4*)g)[t];
  float4 bv = ((const float4*)b)[t];
  ln_store4(yrow + t * 4, (v0 - mean) * rstd * gv.x + bv.x,
            (v1 - mean) * rstd * gv.y + bv.y, (v2 - mean) * rstd * gv.z + bv.z,
            (v3 - mean) * rstd * gv.w + bv.w);
}

template <typename OUT>
__global__ __launch_bounds__(256) void k_ln(const float* __restrict__ h,
                                            const float* __restrict__ g,
                                            const float* __restrict__ b,
                                            OUT* __restrict__ y) {
  int row = blockIdx.x, t = threadIdx.x;
  const float4 v = ((const float4*)(h + (size_t)row * DMODEL))[t];
  ln_rowcore<OUT>(v.x, v.y, v.z, v.w, g, b, y + (size_t)row * DMODEL, t);
}

// ---------------------------------------------------------------------------
// Fused split-K merge + residual + LayerNorm:
//   hnew = hin + bias + sum_ks part[ks];  if (WB) hb := hnew;  y := LN(hnew)
// ---------------------------------------------------------------------------
template <int KS, typename OUT, bool WB>
__global__ __launch_bounds__(256) void k_redln(const float* __restrict__ part,
                                               const float* __restrict__ bias,
                                               const float* __restrict__ hin,
                                               float* __restrict__ hb,
                                               const float* __restrict__ g,
                                               const float* __restrict__ b,
                                               OUT* __restrict__ y) {
  int row = blockIdx.x, t = threadIdx.x;
  size_t base = (size_t)row * DMODEL + t * 4;
  float4 r = *(const float4*)(hin + base);
  float4 bv = *(const float4*)(bias + t * 4);
  float v0 = r.x + bv.x, v1 = r.y + bv.y, v2 = r.z + bv.z, v3 = r.w + bv.w;
#pragma unroll
  for (int ks = 0; ks < KS; ++ks) {
    float4 p = *(const float4*)(part + (size_t)ks * (S_LEN * DMODEL) + base);
    v0 += p.x; v1 += p.y; v2 += p.z; v3 += p.w;
  }
  if (WB) *(float4*)(hb + base) = make_float4(v0, v1, v2, v3);
  ln_rowcore<OUT>(v0, v1, v2, v3, g, b, y + (size_t)row * DMODEL, t);
}

// ---------------------------------------------------------------------------
// Fused RoPE (q,k) + V transpose. Grid (S/64, NHEAD), 256 threads.
// ---------------------------------------------------------------------------
__global__ __launch_bounds__(256) void k_ropetv(const bf16* __restrict__ qkv,
                                                const float* __restrict__ fcos,
                                                const float* __restrict__ fsin,
                                                bf16* __restrict__ qr,
                                                bf16* __restrict__ kr,
                                                bf16* __restrict__ vT) {
  __shared__ bf16 tl[64][65];
  int t = threadIdx.x;
  int hh = blockIdx.y;
  int sb = blockIdx.x * 64;
#pragma unroll
  for (int i = 0; i < 8; ++i) {
    int e = i * 256 + t;
    int p = e & 31, sl = e >> 5;
    int s = sb + sl;
    float c = fcos[s * 32 + p], sn = fsin[s * 32 + p];
    int colq = hh * DHEAD + 2 * p;
    uint32_t rq = *(const uint32_t*)(qkv + (size_t)s * 3 * DMODEL + colq);
    uint32_t rk = *(const uint32_t*)(qkv + (size_t)s * 3 * DMODEL + DMODEL + colq);
    {
      float te = bf2f(rq & 0xffffu), to = bf2f(rq >> 16);
      uint32_t outv = (uint32_t)f2bf(te * c - to * sn) | ((uint32_t)f2bf(te * sn + to * c) << 16);
      *(uint32_t*)(qr + (size_t)s * DMODEL + colq) = outv;
    }
    {
      float te = bf2f(rk & 0xffffu), to = bf2f(rk >> 16);
      uint32_t outv = (uint32_t)f2bf(te * c - to * sn) | ((uint32_t)f2bf(te * sn + to * c) << 16);
      *(uint32_t*)(kr + (size_t)s * DMODEL + colq) = outv;
    }
  }
#pragma unroll
  for (int i = 0; i < 16; ++i) {
    int e = i * 256 + t;
    int sl = e >> 6, d = e & 63;
    tl[sl][d] = qkv[(size_t)(sb + sl) * 3 * DMODEL + 2 * DMODEL + hh * DHEAD + d];
  }
  __syncthreads();
#pragma unroll
  for (int i = 0; i < 16; ++i) {
    int e = i * 256 + t;
    int d = e >> 6, sl = e & 63;
    vT[(size_t)(hh * DHEAD + d) * S_LEN + sb + sl] = tl[sl][d];
  }
}

// ---------------------------------------------------------------------------
// GEMM (session-best config): BM x 128 tile, BK=64, T2 XOR swizzle, T1 XCD
// swizzle, split-K via z, counted-vmcnt 2-deep prefetch, raw s_barrier.
// EPI 0: bias -> bf16.  EPI 2: gelu(bias) -> bf16.  EPI 3: raw fp32 partial.
// ---------------------------------------------------------------------------
template <int EPI, int BM>
__global__ __launch_bounds__(256) void k_gemm2(const bf16* __restrict__ A,
                                               const bf16* __restrict__ BT,
                                               const float* __restrict__ bias,
                                               void* __restrict__ out,
                                               int M, int N, int K, int Kc) {
  constexpr int MF = BM / 32;  // m-frags per wave
  __shared__ bf16 As[2][BM * 64];
  __shared__ bf16 Bs[2][128 * 64];
  int t = threadIdx.x;
  int w = t >> 6, l = t & 63, lr = l & 15, lg = l >> 4;

  int nxy = gridDim.x * gridDim.y;
  int bid = blockIdx.y * gridDim.x + blockIdx.x;
  int chk8 = nxy >> 3;
  int swz = (bid & 7) * chk8 + (bid >> 3);
  int bx = swz % gridDim.x, by = swz / gridDim.x;
  int bm = bx * BM, bn = by * 128;
  int k0 = blockIdx.z * Kc;
  int wm = (w >> 1) * (BM / 2), wn = (w & 1) * 64;

  f32x4 zero4 = {0.f, 0.f, 0.f, 0.f};
  f32x4 acc[MF][4];
#pragma unroll
  for (int mf = 0; mf < MF; ++mf)
#pragma unroll
    for (int nf = 0; nf < 4; ++nf) acc[mf][nf] = zero4;

  auto stage = [&](int buf, int kk) {
#pragma unroll
    for (int i = 0; i < BM / 32; ++i) {
      int chunk = i * 256 + t;
      int row = chunk >> 3;
      int scol = ((chunk ^ row) & 7) << 3;
      __builtin_amdgcn_global_load_lds(
          (__attribute__((address_space(1))) void*)(A + (size_t)(bm + row) * K + kk + scol),
          (__attribute__((address_space(3))) void*)(&As[buf][chunk * 8]), 16, 0, 0);
    }
#pragma unroll
    for (int i = 0; i < 4; ++i) {
      int chunk = i * 256 + t;
      int row = chunk >> 3;
      int scol = ((chunk ^ row) & 7) << 3;
      __builtin_amdgcn_global_load_lds(
          (__attribute__((address_space(1))) void*)(BT + (size_t)(bn + row) * K + kk + scol),
          (__attribute__((address_space(3))) void*)(&Bs[buf][chunk * 8]), 16, 0, 0);
    }
  };

  int nt = Kc / 64;
  stage(0, k0);
  stage(1, k0 + 64);  // 2 tiles in flight (nt >= 8 for all our shapes)
  int cur = 0;
  for (int kt = 0; kt < nt; ++kt) {
    // wait for the OLDEST stage (tile kt) only; tile kt+1 stays in flight
    if (kt + 1 < nt) {
      if constexpr (BM == 128)
        asm volatile("s_waitcnt vmcnt(8)" ::: "memory");
      else
        asm volatile("s_waitcnt vmcnt(6)" ::: "memory");
    } else {
      asm volatile("s_waitcnt vmcnt(0)" ::: "memory");
    }
    __builtin_amdgcn_s_barrier();  // all waves' tile-kt loads landed
    __builtin_amdgcn_sched_barrier(0);
    bf16x8 af[2][MF], bfr[2][4];
#pragma unroll
    for (int h = 0; h < 2; ++h) {
#pragma unroll
      for (int mf = 0; mf < MF; ++mf) {
        int row = wm + mf * 16 + lr;
        af[h][mf] = *(const bf16x8*)(&As[cur][row * 64 + ((((h << 2) + lg) ^ (row & 7)) << 3)]);
      }
#pragma unroll
      for (int nf = 0; nf < 4; ++nf) {
        int row = wn + nf * 16 + lr;
        bfr[h][nf] = *(const bf16x8*)(&Bs[cur][row * 64 + ((((h << 2) + lg) ^ (row & 7)) << 3)]);
      }
    }
    asm volatile("s_waitcnt lgkmcnt(0)" ::: "memory");
    __builtin_amdgcn_sched_barrier(0);
    __builtin_amdgcn_s_barrier();  // all waves done reading buf[cur]
    if (kt + 2 < nt) stage(cur, k0 + (kt + 2) * 64);  // refill freed buffer
    __builtin_amdgcn_sched_barrier(0);
#pragma unroll
    for (int h = 0; h < 2; ++h)
#pragma unroll
      for (int mf = 0; mf < MF; ++mf)
#pragma unroll
        for (int nf = 0; nf < 4; ++nf)
          acc[mf][nf] = MFMA16x16(af[h][mf], bfr[h][nf], acc[mf][nf]);
    cur ^= 1;
  }

  if (EPI == 3) {
    float* outf = (float*)out + (size_t)blockIdx.z * ((size_t)M * N);
#pragma unroll
    for (int mf = 0; mf < MF; ++mf)
#pragma unroll
      for (int nf = 0; nf < 4; ++nf) {
        int col = bn + wn + nf * 16 + lr;
        int row0 = bm + wm + mf * 16 + lg * 4;
#pragma unroll
        for (int r = 0; r < 4; ++r)
          outf[(size_t)(row0 + r) * N + col] = acc[mf][nf][r];
      }
  } else {
    bf16* outb = (bf16*)out;
#pragma unroll
    for (int mf = 0; mf < MF; ++mf)
#pragma unroll
      for (int nf = 0; nf < 4; ++nf) {
        int col = bn + wn + nf * 16 + lr;
        float bv = bias[col];
        int row0 = bm + wm + mf * 16 + lg * 4;
#pragma unroll
        for (int r = 0; r < 4; ++r) {
          float v = acc[mf][nf][r] + bv;
          if (EPI == 2)
            v = 0.5f * v * (1.0f + tanhf(0.7978845608028654f * (v + 0.044715f * v * v * v)));
          outb[(size_t)(row0 + r) * N + col] = __float2bfloat16(v);
        }
      }
  }
}

// ---------------------------------------------------------------------------
// Flash attention v7 (stable body: 4-wave split-K, swapped-operand 32x32x16,
// in-register softmax via cvt_pk+permlane, defer-max, 2-deep K register
// pipeline with named registers). VGPR-cliff: no added control flow.
// ---------------------------------------------------------------------------
#define ATTN_TILE(KC0, KC1, KC2, KC3, KN0, KN1, KN2, KN3, IT)                  \
  {                                                                            \
    const int j0 = jbase + (IT) * 32;                                          \
    f32x16 sC;                                                                 \
    _Pragma("unroll") for (int r = 0; r < 16; ++r) sC[r] = 0.f;                \
    __builtin_amdgcn_s_setprio(1);                                             \
    sC = MFMA32x32(KC0, qf0, sC);                                              \
    sC = MFMA32x32(KC1, qf1, sC);                                              \
    sC = MFMA32x32(KC2, qf2, sC);                                              \
    sC = MFMA32x32(KC3, qf3, sC);                                              \
    __builtin_amdgcn_s_setprio(0);                                             \
    const bf16* vbase = vrow + j0;                                             \
    bf16x8 va00 = *(const bf16x8*)(vbase);                                     \
    bf16x8 va01 = *(const bf16x8*)(vbase + 16);                                \
    bf16x8 va10 = *(const bf16x8*)(vbase + 32 * S_LEN);                        \
    bf16x8 va11 = *(const bf16x8*)(vbase + 32 * S_LEN + 16);                   \
    {                                                                          \
      int jn = j0 + 32;                                                        \
      int jmax = jbase + 480;                                                  \
      jn = (jn > jmax) ? jmax : jn;                                            \
      const bf16* kn = krow + (size_t)jn * DMODEL;                             \
      KN0 = *(const bf16x8*)(kn);                                              \
      KN1 = *(const bf16x8*)(kn + 16);                                         \
      KN2 = *(const bf16x8*)(kn + 32);                                         \
      KN3 = *(const bf16x8*)(kn + 48);                                         \
    }                                                                          \
    int tt = j0 + hi * 4 - sl0;                                                \
    _Pragma("unroll") for (int r = 0; r < 16; ++r) {                           \
      int ku = tt + ((r & 3) + 8 * (r >> 2));                                  \
      float fb = ((uint32_t)ku < spanu) ? LOG2E : 0.0f;                        \
      sC[r] = sC[r] * C1 + fb;                                                 \
    }                                                                          \
    float rm = sC[0];                                                          \
    _Pragma("unroll") for (int r = 1; r < 16; ++r) rm = fmaxf(rm, sC[r]);      \
    uint32_t ra = __builtin_bit_cast(uint32_t, rm), rb = ra;                   \
    pl32swap(ra, rb);                                                          \
    float rmax =                                                               \
        fmaxf(__builtin_bit_cast(float, ra), __builtin_bit_cast(float, rb));   \
    if (__any(rmax > m_r + 8.0f)) {                                            \
      float mn = fmaxf(m_r, rmax);                                             \
      float fs = EXP2(m_r - mn);                                               \
      m_r = mn;                                                                \
      l_r *= fs;                                                               \
      _Pragma("unroll") for (int r = 0; r < 16; ++r) {                         \
        oC0[r] *= fs;                                                          \
        oC1[r] *= fs;                                                          \
      }                                                                        \
    }                                                                          \
    _Pragma("unroll") for (int r = 0; r < 16; ++r) {                           \
      float pv = EXP2(sC[r] - m_r);                                            \
      sC[r] = pv;                                                              \
      l_r += pv;                                                               \
    }                                                                          \
    uint32_t u0 = cvtpk(sC[0], sC[1]), u1 = cvtpk(sC[2], sC[3]);               \
    uint32_t u2 = cvtpk(sC[4], sC[5]), u3 = cvtpk(sC[6], sC[7]);               \
    uint32_t u4 = cvtpk(sC[8], sC[9]), u5 = cvtpk(sC[10], sC[11]);             \
    uint32_t u6 = cvtpk(sC[12], sC[13]), u7 = cvtpk(sC[14], sC[15]);           \
    pl32swap(u0, u2);                                                          \
    pl32swap(u1, u3);                                                          \
    pl32swap(u4, u6);                                                          \
    pl32swap(u5, u7);                                                          \
    i32x4 pi0 = {(int)u0, (int)u1, (int)u2, (int)u3};                          \
    i32x4 pi1 = {(int)u4, (int)u5, (int)u6, (int)u7};                          \
    bf16x8 pb0 = __builtin_bit_cast(bf16x8, pi0);                              \
    bf16x8 pb1 = __builtin_bit_cast(bf16x8, pi1);                              \
    __builtin_amdgcn_s_setprio(1);                                             \
    oC0 = MFMA32x32(va00, pb0, oC0);                                           \
    oC0 = MFMA32x32(va01, pb1, oC0);                                           \
    oC1 = MFMA32x32(va10, pb0, oC1);                                           \
    oC1 = MFMA32x32(va11, pb1, oC1);                                           \
    __builtin_amdgcn_s_setprio(0);                                             \
  }

__global__ __launch_bounds__(256, 4) void k_attn(const bf16* __restrict__ qr,
                                                 const bf16* __restrict__ kr,
                                                 const bf16* __restrict__ vT,
                                                 const int* __restrict__ offs,
                                                 bf16* __restrict__ ao) {
  __shared__ float oO[4][64][33];
  __shared__ float mM[4][32];
  __shared__ float lL[4][32];

  int t = threadIdx.x, w = t >> 6, l = t & 63;
  int ql = l & 31, hi = l >> 5, hi8 = hi * 8;
  int hh = blockIdx.x, qb = blockIdx.y * 32;
  int h64 = hh * DHEAD;

  constexpr float LOG2E = 1.4426950408889634f;
  constexpr float C1 = 0.125f * LOG2E;

  int q = qb + ql;
  int o0 = offs[0], o1 = offs[1], o2 = offs[2], o3 = offs[3], o4 = offs[4];
  int sl0 = -1073741824, sh0 = 1073741824;
  sl0 = (o0 <= q) ? o0 : sl0;
  sl0 = (o1 <= q) ? o1 : sl0;
  sl0 = (o2 <= q) ? o2 : sl0;
  sl0 = (o3 <= q) ? o3 : sl0;
  sl0 = (o4 <= q) ? o4 : sl0;
  sh0 = (o4 > q) ? o4 : sh0;
  sh0 = (o3 > q) ? o3 : sh0;
  sh0 = (o2 > q) ? o2 : sh0;
  sh0 = (o1 > q) ? o1 : sh0;
  sh0 = (o0 > q) ? o0 : sh0;
  uint32_t spanu = (uint32_t)(sh0 - sl0);

  const bf16* qbase = qr + (size_t)q * DMODEL + h64 + hi8;
  bf16x8 qf0 = *(const bf16x8*)(qbase);
  bf16x8 qf1 = *(const bf16x8*)(qbase + 16);
  bf16x8 qf2 = *(const bf16x8*)(qbase + 32);
  bf16x8 qf3 = *(const bf16x8*)(qbase + 48);

  f32x16 oC0, oC1;
#pragma unroll
  for (int r = 0; r < 16; ++r) { oC0[r] = 0.f; oC1[r] = 0.f; }
  float m_r = -1e30f, l_r = 0.f;

  const bf16* vrow = vT + (size_t)(h64 + ql) * S_LEN + hi8;
  const bf16* krow = kr + (size_t)ql * DMODEL + h64 + hi8;
  int jbase = w * 512;

  bf16x8 kA0, kA1, kA2, kA3, kB0, kB1, kB2, kB3;
  {
    const bf16* kb = krow + (size_t)jbase * DMODEL;
    kA0 = *(const bf16x8*)(kb);
    kA1 = *(const bf16x8*)(kb + 16);
    kA2 = *(const bf16x8*)(kb + 32);
    kA3 = *(const bf16x8*)(kb + 48);
  }

  for (int itp = 0; itp < 8; ++itp) {
    ATTN_TILE(kA0, kA1, kA2, kA3, kB0, kB1, kB2, kB3, itp * 2);
    ATTN_TILE(kB0, kB1, kB2, kB3, kA0, kA1, kA2, kA3, itp * 2 + 1);
  }

  {
    uint32_t la = __builtin_bit_cast(uint32_t, l_r), lb = la;
    pl32swap(la, lb);
    l_r = __builtin_bit_cast(float, la) + __builtin_bit_cast(float, lb);
  }
  if (hi == 0) {
    mM[w][ql] = m_r;
    lL[w][ql] = l_r;
  }
#pragma unroll
  for (int r = 0; r < 16; ++r) {
    int d = (r & 3) + 8 * (r >> 2) + 4 * hi;
    oO[w][d][ql] = oC0[r];
    oO[w][d + 32][ql] = oC1[r];
  }
  __syncthreads();

  {
    int mq = t & 31, dbse = (t >> 5) * 8;
    float m0 = mM[0][mq], m1 = mM[1][mq], m2 = mM[2][mq], m3 = mM[3][mq];
    float ms = fmaxf(fmaxf(m0, m1), fmaxf(m2, m3));
    float a0 = EXP2(m0 - ms), a1 = EXP2(m1 - ms), a2 = EXP2(m2 - ms), a3 = EXP2(m3 - ms);
    float ll = a0 * lL[0][mq] + a1 * lL[1][mq] + a2 * lL[2][mq] + a3 * lL[3][mq];
    float inv = 1.0f / ll;
    uint4 pkv;
    uint32_t pw[4];
#pragma unroll
    for (int i = 0; i < 4; ++i) {
      int d0 = dbse + 2 * i, d1 = dbse + 2 * i + 1;
      float e0 = (a0 * oO[0][d0][mq] + a1 * oO[1][d0][mq] + a2 * oO[2][d0][mq] +
                  a3 * oO[3][d0][mq]) * inv;
      float e1 = (a0 * oO[0][d1][mq] + a1 * oO[1][d1][mq] + a2 * oO[2][d1][mq] +
                  a3 * oO[3][d1][mq]) * inv;
      pw[i] = (uint32_t)f2bf(e0) | ((uint32_t)f2bf(e1) << 16);
    }
    pkv.x = pw[0]; pkv.y = pw[1]; pkv.z = pw[2]; pkv.w = pw[3];
    *(uint4*)(ao + (size_t)(qb + mq) * DMODEL + h64 + dbse) = pkv;
  }
}

// ---------------------------------------------------------------------------
extern "C" void kernel_launch(void* const* d_in, const int* in_sizes, int n_in,
                              void* d_out, int out_size, void* d_ws, size_t ws_size,
                              hipStream_t stream) {
  const float* x = (const float*)d_in[0];
  const int* offs = (const int*)d_in[1];
  const float* fcos = (const float*)d_in[2];
  const float* fsin = (const float*)d_in[3];
  const float* ln0g = (const float*)d_in[4];
  const float* ln0b = (const float*)d_in[5];
  const float* ln1g = (const float*)d_in[6];
  const float* ln1b = (const float*)d_in[7];
  const float* wqkv = (const float*)d_in[8];
  const float* bqkv = (const float*)d_in[9];
  const float* wo = (const float*)d_in[10];
  const float* bo = (const float*)d_in[11];
  const float* wu = (const float*)d_in[12];
  const float* bu = (const float*)d_in[13];
  const float* wd = (const float*)d_in[14];
  const float* bd = (const float*)d_in[15];
  const float* lnfg = (const float*)d_in[16];
  const float* lnfb = (const float*)d_in[17];

  char* ws = (char*)d_ws;
  size_t off = 0;
  auto alloc = [&](size_t bytes) -> void* {
    void* p = ws + off;
    off += (bytes + 255) & ~(size_t)255;
    return p;
  };
  bf16* wqkvT = (bf16*)alloc((size_t)NLAYER * 3 * DMODEL * DMODEL * 2);
  bf16* woT = (bf16*)alloc((size_t)NLAYER * DMODEL * DMODEL * 2);
  bf16* wuT = (bf16*)alloc((size_t)NLAYER * DMODEL * FFDIM * 2);
  bf16* wdT = (bf16*)alloc((size_t)NLAYER * FFDIM * DMODEL * 2);
  float* hbuf = (float*)alloc((size_t)S_LEN * DMODEL * 4);
  bf16* ybuf = (bf16*)alloc((size_t)S_LEN * DMODEL * 2);   // partDN head space
  bf16* qkv = (bf16*)alloc((size_t)S_LEN * 3 * DMODEL * 2);
  bf16* qrb = (bf16*)alloc((size_t)S_LEN * DMODEL * 2);
  bf16* krb = (bf16*)alloc((size_t)S_LEN * DMODEL * 2);
  bf16* vTb = (bf16*)alloc((size_t)S_LEN * DMODEL * 2);
  bf16* aob = (bf16*)alloc((size_t)S_LEN * DMODEL * 2);
  bf16* midb = (bf16*)alloc((size_t)S_LEN * FFDIM * 2);
  bf16* ybuf2 = (bf16*)alloc((size_t)S_LEN * DMODEL * 2);  // LN outputs (A operand)

  float* partWO = (float*)qkv;
  float* partDN = (float*)ybuf;

  // all 8 weight casts in ONE dispatch (float4 loads, ushort4 stores)
  k_tcast_all<<<6144, 256, 0, stream>>>(wqkv, wo, wu, wd, wqkvT, woT, wuT, wdT);

  // layer-0 entry LN reads x directly (no x->hbuf memcpy; layer-0 WO-redln
  // uses x as the residual source and performs the first hbuf write)
  k_ln<bf16><<<S_LEN, 256, 0, stream>>>(x, ln0g, ln0b, ybuf2);

  for (int ly = 0; ly < NLAYER; ++ly) {
    // QKV: M=2048, N=3072, K=1024  (grid 16x24 = 384)
    k_gemm2<0, 128><<<dim3(S_LEN / 128, 3 * DMODEL / 128, 1), 256, 0, stream>>>(
        ybuf2, wqkvT + (size_t)ly * 3 * DMODEL * DMODEL, bqkv + ly * 3 * DMODEL, qkv,
        S_LEN, 3 * DMODEL, DMODEL, DMODEL);
    k_ropetv<<<dim3(S_LEN / 64, NHEAD), 256, 0, stream>>>(qkv, fcos, fsin, qrb, krb, vTb);
    k_attn<<<dim3(NHEAD, S_LEN / 32), 256, 0, stream>>>(qrb, krb, vTb, offs, aob);
    // WO: M=2048, N=1024, K=1024, split-K 2, BM=64  (xy grid 32x8 = 256)
    k_gemm2<3, 64><<<dim3(S_LEN / 64, DMODEL / 128, 2), 256, 0, stream>>>(
        aob, woT + (size_t)ly * DMODEL * DMODEL, nullptr, partWO,
        S_LEN, DMODEL, DMODEL, DMODEL / 2);
    // fused: hbuf = (ly? hbuf : x) + bo + sum(partWO); ybuf2 = LN1(hbuf)
    k_redln<2, bf16, true><<<S_LEN, 256, 0, stream>>>(
        partWO, bo + ly * DMODEL, ly == 0 ? x : hbuf, hbuf,
        ln1g + ly * DMODEL, ln1b + ly * DMODEL, ybuf2);
    // UP: M=2048, N=4096, K=1024  (grid 16x32 = 512)
    k_gemm2<2, 128><<<dim3(S_LEN / 128, FFDIM / 128, 1), 256, 0, stream>>>(
        ybuf2, wuT + (size_t)ly * DMODEL * FFDIM, bu + ly * FFDIM, midb,
        S_LEN, FFDIM, DMODEL, DMODEL);
    // DOWN: M=2048, N=1024, K=4096, split-K 4, BM=128  (xy grid 16x8 = 128)
    k_gemm2<3, 128><<<dim3(S_LEN / 128, DMODEL / 128, 4), 256, 0, stream>>>(
        midb, wdT + (size_t)ly * FFDIM * DMODEL, nullptr, partDN,
        S_LEN, DMODEL, FFDIM, FFDIM / 4);
    if (ly + 1 < NLAYER) {
      k_redln<4, bf16, true><<<S_LEN, 256, 0, stream>>>(
          partDN, bd + ly * DMODEL, hbuf, hbuf, ln0g + (ly + 1) * DMODEL,
          ln0b + (ly + 1) * DMODEL, ybuf2);
    } else {
      // final: no hbuf writeback (dead), LNf straight to d_out
      k_redln<4, float, false><<<S_LEN, 256, 0, stream>>>(
          partDN, bd + ly * DMODEL, hbuf, hbuf, lnfg, lnfb, (float*)d_out);
    }
  }
}